// Round 1
// baseline (8645.341 us; speedup 1.0000x reference)
//
#include <hip/hip_runtime.h>
#include <math.h>

#define NN 50000
#define NE 800000
#define NG 64
#define DIN 64
#define DEA 16
#define H 128
#define NL 4

__device__ __forceinline__ float4 ld4(const float* p) { return *reinterpret_cast<const float4*>(p); }
__device__ __forceinline__ void st4(float* p, float4 v) { *reinterpret_cast<float4*>(p) = v; }
__device__ __forceinline__ void fma4(float4& a, float s, float4 w) {
    a.x = fmaf(s, w.x, a.x); a.y = fmaf(s, w.y, a.y);
    a.z = fmaf(s, w.z, a.z); a.w = fmaf(s, w.w, a.w);
}
__device__ __forceinline__ float4 f4add(float4 a, float4 b) {
    return make_float4(a.x + b.x, a.y + b.y, a.z + b.z, a.w + b.w);
}
__device__ __forceinline__ float4 relu4(float4 a) {
    return make_float4(fmaxf(a.x, 0.f), fmaxf(a.y, 0.f), fmaxf(a.z, 0.f), fmaxf(a.w, 0.f));
}
__device__ __forceinline__ unsigned fkey(float f) {
    unsigned b = __float_as_uint(f);
    return (b & 0x80000000u) ? ~b : (b | 0x80000000u);
}
__device__ __forceinline__ float funkey(unsigned k) {
    unsigned b = (k & 0x80000000u) ? (k ^ 0x80000000u) : ~k;
    return __uint_as_float(b);
}

// h = relu(x @ encW + encb), x:[NN,64], W:[64,128]
__global__ __launch_bounds__(256) void encoder_kernel(const float* __restrict__ x,
    const float* __restrict__ W, const float* __restrict__ b, float* __restrict__ h)
{
    const int tid = threadIdx.x, q = tid & 31, no = tid >> 5;
    const int nbase = blockIdx.x * 64;
    float4 bv = ld4(b + 4 * q);
    float4 acc[8];
#pragma unroll
    for (int i = 0; i < 8; ++i) acc[i] = bv;
    for (int k4 = 0; k4 < 16; ++k4) {
        const float* wp = W + (4 * k4) * H + 4 * q;
        float4 w0 = ld4(wp), w1 = ld4(wp + H), w2 = ld4(wp + 2 * H), w3 = ld4(wp + 3 * H);
#pragma unroll
        for (int i = 0; i < 8; ++i) {
            int n = nbase + no * 8 + i; n = n < NN ? n : NN - 1;
            float4 a = ld4(x + n * DIN + 4 * k4);
            fma4(acc[i], a.x, w0); fma4(acc[i], a.y, w1);
            fma4(acc[i], a.z, w2); fma4(acc[i], a.w, w3);
        }
    }
#pragma unroll
    for (int i = 0; i < 8; ++i) {
        int n = nbase + no * 8 + i;
        if (n < NN) st4(h + n * H + 4 * q, relu4(acc[i]));
    }
}

__global__ __launch_bounds__(256) void dist2_kernel(const float* __restrict__ pos,
    const int* __restrict__ ei, float* __restrict__ d2)
{
    int e = blockIdx.x * 256 + threadIdx.x;
    if (e >= NE) return;
    int s = ei[e], d = ei[NE + e];
    float dx = pos[s * 3 + 0] - pos[d * 3 + 0];
    float dy = pos[s * 3 + 1] - pos[d * 3 + 1];
    float dz = pos[s * 3 + 2] - pos[d * 3 + 2];
    d2[e] = dx * dx + dy * dy + dz * dz;
}

// Pd = h @ W1[0:128], Ps = h @ W1[128:256]   (W1 = eW1[l], [273][128])
__global__ __launch_bounds__(256) void proj_kernel(const float* __restrict__ h,
    const float* __restrict__ W1, float* __restrict__ Pd, float* __restrict__ Ps)
{
    const int tid = threadIdx.x, q = tid & 31, no = tid >> 5;
    const int nbase = blockIdx.x * 64;
    float4 ad[8], as[8];
#pragma unroll
    for (int i = 0; i < 8; ++i) { ad[i] = make_float4(0, 0, 0, 0); as[i] = make_float4(0, 0, 0, 0); }
    for (int k4 = 0; k4 < 32; ++k4) {
        const float* wdp = W1 + (4 * k4) * H + 4 * q;
        const float* wsp = W1 + (128 + 4 * k4) * H + 4 * q;
        float4 wd0 = ld4(wdp), wd1 = ld4(wdp + H), wd2 = ld4(wdp + 2 * H), wd3 = ld4(wdp + 3 * H);
        float4 ws0 = ld4(wsp), ws1 = ld4(wsp + H), ws2 = ld4(wsp + 2 * H), ws3 = ld4(wsp + 3 * H);
#pragma unroll
        for (int i = 0; i < 8; ++i) {
            int n = nbase + no * 8 + i; n = n < NN ? n : NN - 1;
            float4 a = ld4(h + n * H + 4 * k4);
            fma4(ad[i], a.x, wd0); fma4(ad[i], a.y, wd1); fma4(ad[i], a.z, wd2); fma4(ad[i], a.w, wd3);
            fma4(as[i], a.x, ws0); fma4(as[i], a.y, ws1); fma4(as[i], a.z, ws2); fma4(as[i], a.w, ws3);
        }
    }
#pragma unroll
    for (int i = 0; i < 8; ++i) {
        int n = nbase + no * 8 + i;
        if (n < NN) { st4(Pd + n * H + 4 * q, ad[i]); st4(Ps + n * H + 4 * q, as[i]); }
    }
}

// per edge: t = relu(Pd[dst] + Ps[src] + ea@Wea + d2*wd + b1); m = relu(t@W2 + b2); agg[dst] += m
__global__ __launch_bounds__(256) void edge_kernel(
    const float* __restrict__ Pd, const float* __restrict__ Ps,
    const float* __restrict__ ea, const float* __restrict__ d2,
    const int* __restrict__ ei,
    const float* __restrict__ W1, const float* __restrict__ b1,
    const float* __restrict__ W2, const float* __restrict__ b2,
    float* __restrict__ agg)
{
    __shared__ float tls[64 * H];
    const int tid = threadIdx.x, q = tid & 31, eo = tid >> 5;
    const int ebase = blockIdx.x * 64;
    int dsts[8];
    const float* Wea = W1 + 256 * H;
    const float* wdv = W1 + 272 * H;
    float4 b1v = ld4(b1 + 4 * q);
    float4 wdq = ld4(wdv + 4 * q);
#pragma unroll
    for (int i = 0; i < 8; ++i) {
        int el = eo * 8 + i, e = ebase + el;
        int s = ei[e], d = ei[NE + e];
        dsts[i] = d;
        float4 acc = f4add(ld4(Pd + (size_t)d * H + 4 * q), ld4(Ps + (size_t)s * H + 4 * q));
        acc = f4add(acc, b1v);
        fma4(acc, d2[e], wdq);
        const float4* eav = reinterpret_cast<const float4*>(ea + (size_t)e * DEA);
#pragma unroll
        for (int k4 = 0; k4 < 4; ++k4) {
            float4 av = eav[k4];
            fma4(acc, av.x, ld4(Wea + (4 * k4 + 0) * H + 4 * q));
            fma4(acc, av.y, ld4(Wea + (4 * k4 + 1) * H + 4 * q));
            fma4(acc, av.z, ld4(Wea + (4 * k4 + 2) * H + 4 * q));
            fma4(acc, av.w, ld4(Wea + (4 * k4 + 3) * H + 4 * q));
        }
        st4(&tls[el * H + 4 * q], relu4(acc));
    }
    __syncthreads();
    float4 b2v = ld4(b2 + 4 * q);
    float4 acc[8];
#pragma unroll
    for (int i = 0; i < 8; ++i) acc[i] = b2v;
    for (int k4 = 0; k4 < 32; ++k4) {
        const float* wp = W2 + (4 * k4) * H + 4 * q;
        float4 w0 = ld4(wp), w1 = ld4(wp + H), w2 = ld4(wp + 2 * H), w3 = ld4(wp + 3 * H);
#pragma unroll
        for (int i = 0; i < 8; ++i) {
            float4 t = *reinterpret_cast<const float4*>(&tls[(eo * 8 + i) * H + 4 * k4]);
            fma4(acc[i], t.x, w0); fma4(acc[i], t.y, w1);
            fma4(acc[i], t.z, w2); fma4(acc[i], t.w, w3);
        }
    }
#pragma unroll
    for (int i = 0; i < 8; ++i) {
        float4 m = relu4(acc[i]);
        float* ap = agg + (size_t)dsts[i] * H + 4 * q;
        atomicAdd(ap + 0, m.x); atomicAdd(ap + 1, m.y);
        atomicAdd(ap + 2, m.z); atomicAdd(ap + 3, m.w);
    }
}

// h' = relu([h,agg] @ nW1 + nb1) @ nW2 + nb2   (no final relu)
__global__ __launch_bounds__(256) void node_kernel(
    const float* __restrict__ h, const float* __restrict__ agg,
    const float* __restrict__ W1, const float* __restrict__ b1,
    const float* __restrict__ W2, const float* __restrict__ b2,
    float* __restrict__ hout)
{
    __shared__ float uls[64 * H];
    const int tid = threadIdx.x, q = tid & 31, no = tid >> 5;
    const int nbase = blockIdx.x * 64;
    float4 acc[8];
    float4 b1v = ld4(b1 + 4 * q);
#pragma unroll
    for (int i = 0; i < 8; ++i) acc[i] = b1v;
    for (int k4 = 0; k4 < 32; ++k4) {
        const float* wp = W1 + (4 * k4) * H + 4 * q;
        float4 w0 = ld4(wp), w1 = ld4(wp + H), w2 = ld4(wp + 2 * H), w3 = ld4(wp + 3 * H);
#pragma unroll
        for (int i = 0; i < 8; ++i) {
            int n = nbase + no * 8 + i; n = n < NN ? n : NN - 1;
            float4 a = ld4(h + n * H + 4 * k4);
            fma4(acc[i], a.x, w0); fma4(acc[i], a.y, w1);
            fma4(acc[i], a.z, w2); fma4(acc[i], a.w, w3);
        }
    }
    for (int k4 = 0; k4 < 32; ++k4) {
        const float* wp = W1 + (128 + 4 * k4) * H + 4 * q;
        float4 w0 = ld4(wp), w1 = ld4(wp + H), w2 = ld4(wp + 2 * H), w3 = ld4(wp + 3 * H);
#pragma unroll
        for (int i = 0; i < 8; ++i) {
            int n = nbase + no * 8 + i; n = n < NN ? n : NN - 1;
            float4 a = ld4(agg + n * H + 4 * k4);
            fma4(acc[i], a.x, w0); fma4(acc[i], a.y, w1);
            fma4(acc[i], a.z, w2); fma4(acc[i], a.w, w3);
        }
    }
#pragma unroll
    for (int i = 0; i < 8; ++i) st4(&uls[(no * 8 + i) * H + 4 * q], relu4(acc[i]));
    __syncthreads();
    float4 acc2[8];
    float4 b2v = ld4(b2 + 4 * q);
#pragma unroll
    for (int i = 0; i < 8; ++i) acc2[i] = b2v;
    for (int k4 = 0; k4 < 32; ++k4) {
        const float* wp = W2 + (4 * k4) * H + 4 * q;
        float4 w0 = ld4(wp), w1 = ld4(wp + H), w2 = ld4(wp + 2 * H), w3 = ld4(wp + 3 * H);
#pragma unroll
        for (int i = 0; i < 8; ++i) {
            float4 t = *reinterpret_cast<const float4*>(&uls[(no * 8 + i) * H + 4 * k4]);
            fma4(acc2[i], t.x, w0); fma4(acc2[i], t.y, w1);
            fma4(acc2[i], t.z, w2); fma4(acc2[i], t.w, w3);
        }
    }
#pragma unroll
    for (int i = 0; i < 8; ++i) {
        int n = nbase + no * 8 + i;
        if (n < NN) st4(hout + n * H + 4 * q, acc2[i]);  // NO relu on final
    }
}

// batch is sorted: run-length local reduce then one atomic per run
__global__ __launch_bounds__(256) void pool_kernel(const float* __restrict__ h,
    const int* __restrict__ batch, float* __restrict__ ssum,
    unsigned int* __restrict__ smaxk, float* __restrict__ cnt)
{
    const int tid = threadIdx.x, j = tid & 127, half = tid >> 7;
    const int nbase = blockIdx.x * 64;
    int cur = -1, rc = 0;
    float s = 0.f, mx = 0.f;
    for (int i = 0; i < 32; ++i) {
        int n = nbase + 2 * i + half;
        if (n >= NN) break;
        int g = batch[n];
        float v = h[(size_t)n * H + j];
        if (g != cur) {
            if (cur >= 0) {
                atomicAdd(&ssum[cur * H + j], s);
                atomicMax(&smaxk[cur * H + j], fkey(mx));
                if (j == 0) atomicAdd(&cnt[cur], (float)rc);
            }
            cur = g; s = v; mx = v; rc = 1;
        } else { s += v; mx = fmaxf(mx, v); rc++; }
    }
    if (cur >= 0) {
        atomicAdd(&ssum[cur * H + j], s);
        atomicMax(&smaxk[cur * H + j], fkey(mx));
        if (j == 0) atomicAdd(&cnt[cur], (float)rc);
    }
}

__global__ __launch_bounds__(128) void readout_kernel(const float* __restrict__ ssum,
    const unsigned int* __restrict__ smaxk, const float* __restrict__ cnt,
    const float* __restrict__ rW1, const float* __restrict__ rb1,
    const float* __restrict__ rW2, const float* __restrict__ rb2,
    const float* __restrict__ rW3, const float* __restrict__ rb3,
    float* __restrict__ out)
{
    __shared__ float p[384], h1[128], h2[64];
    const int g = blockIdx.x, j = threadIdx.x;
    float c = fmaxf(cnt[g], 1.0f);
    float sv = ssum[g * H + j];
    p[j] = sv / c;
    p[128 + j] = funkey(smaxk[g * H + j]);
    p[256 + j] = sv;
    __syncthreads();
    float a = rb1[j];
    for (int k = 0; k < 384; ++k) a = fmaf(p[k], rW1[k * H + j], a);
    h1[j] = fmaxf(a, 0.f);
    __syncthreads();
    if (j < 64) {
        float a2 = rb2[j];
        for (int k = 0; k < 128; ++k) a2 = fmaf(h1[k], rW2[k * 64 + j], a2);
        h2[j] = fmaxf(a2, 0.f);
    }
    __syncthreads();
    if (j < 64) {
        float t = h2[j] * rW3[j];
        for (int off = 32; off; off >>= 1) t += __shfl_down(t, off);
        if (j == 0) {
            float z = t + rb3[0];
            out[g] = z > 20.f ? z : log1pf(expf(z));
        }
    }
}

extern "C" void kernel_launch(void* const* d_in, const int* in_sizes, int n_in,
                              void* d_out, int out_size, void* d_ws, size_t ws_size,
                              hipStream_t stream)
{
    const float* x    = (const float*)d_in[0];
    const float* pos  = (const float*)d_in[1];
    const float* ea   = (const float*)d_in[2];
    const int*   ei   = (const int*)d_in[3];
    const int*   batch= (const int*)d_in[4];
    const float* encW = (const float*)d_in[5];
    const float* encb = (const float*)d_in[6];
    const float* eW1  = (const float*)d_in[7];
    const float* eb1  = (const float*)d_in[8];
    const float* eW2  = (const float*)d_in[9];
    const float* eb2  = (const float*)d_in[10];
    const float* nW1  = (const float*)d_in[11];
    const float* nb1  = (const float*)d_in[12];
    const float* nW2  = (const float*)d_in[13];
    const float* nb2  = (const float*)d_in[14];
    const float* rW1  = (const float*)d_in[15];
    const float* rb1  = (const float*)d_in[16];
    const float* rW2  = (const float*)d_in[17];
    const float* rb2  = (const float*)d_in[18];
    const float* rW3  = (const float*)d_in[19];
    const float* rb3  = (const float*)d_in[20];

    char* w = (char*)d_ws;
    size_t o = 0;
    auto alloc = [&](size_t bytes) -> char* {
        char* p = w + o; o += (bytes + 255) / 256 * 256; return p;
    };
    float* hA   = (float*)alloc((size_t)NN * H * 4);
    float* hB   = (float*)alloc((size_t)NN * H * 4);
    float* Pd   = (float*)alloc((size_t)NN * H * 4);
    float* Ps   = (float*)alloc((size_t)NN * H * 4);
    float* agg  = (float*)alloc((size_t)NN * H * 4);
    float* d2   = (float*)alloc((size_t)NE * 4);
    float* ssum = (float*)alloc((size_t)NG * H * 4);
    unsigned int* smaxk = (unsigned int*)alloc((size_t)NG * H * 4);
    float* cnt  = (float*)alloc((size_t)NG * 4);
    (void)ws_size; (void)in_sizes; (void)n_in; (void)out_size;

    const int NB = (NN + 63) / 64;
    encoder_kernel<<<NB, 256, 0, stream>>>(x, encW, encb, hA);
    dist2_kernel<<<(NE + 255) / 256, 256, 0, stream>>>(pos, ei, d2);

    float* hcur = hA;
    float* hnext = hB;
    for (int l = 0; l < NL; ++l) {
        hipMemsetAsync(agg, 0, (size_t)NN * H * 4, stream);
        const float* W1 = eW1 + (size_t)l * 273 * H;
        proj_kernel<<<NB, 256, 0, stream>>>(hcur, W1, Pd, Ps);
        edge_kernel<<<NE / 64, 256, 0, stream>>>(Pd, Ps, ea, d2, ei,
            W1, eb1 + l * H, eW2 + (size_t)l * H * H, eb2 + l * H, agg);
        node_kernel<<<NB, 256, 0, stream>>>(hcur, agg,
            nW1 + (size_t)l * 256 * H, nb1 + l * H, nW2 + (size_t)l * H * H, nb2 + l * H, hnext);
        float* tmp = hcur; hcur = hnext; hnext = tmp;
    }

    hipMemsetAsync(ssum, 0, (size_t)NG * H * 4, stream);
    hipMemsetAsync(smaxk, 0, (size_t)NG * H * 4, stream);
    hipMemsetAsync(cnt, 0, (size_t)NG * 4, stream);
    pool_kernel<<<NB, 256, 0, stream>>>(hcur, batch, ssum, smaxk, cnt);
    readout_kernel<<<NG, 128, 0, stream>>>(ssum, smaxk, cnt,
        rW1, rb1, rW2, rb2, rW3, rb3, (float*)d_out);
}

// Round 2
// 6961.771 us; speedup vs baseline: 1.2418x; 1.2418x over previous
//
#include <hip/hip_runtime.h>
#include <math.h>

#define NN 50000
#define NE 800000
#define NG 64
#define DIN 64
#define DEA 16
#define H 128
#define NL 4

__device__ __forceinline__ float4 ld4(const float* p) { return *reinterpret_cast<const float4*>(p); }
__device__ __forceinline__ void st4(float* p, float4 v) { *reinterpret_cast<float4*>(p) = v; }
__device__ __forceinline__ void fma4(float4& a, float s, float4 w) {
    a.x = fmaf(s, w.x, a.x); a.y = fmaf(s, w.y, a.y);
    a.z = fmaf(s, w.z, a.z); a.w = fmaf(s, w.w, a.w);
}
__device__ __forceinline__ float4 f4add(float4 a, float4 b) {
    return make_float4(a.x + b.x, a.y + b.y, a.z + b.z, a.w + b.w);
}
__device__ __forceinline__ float4 relu4(float4 a) {
    return make_float4(fmaxf(a.x, 0.f), fmaxf(a.y, 0.f), fmaxf(a.z, 0.f), fmaxf(a.w, 0.f));
}
__device__ __forceinline__ unsigned fkey(float f) {
    unsigned b = __float_as_uint(f);
    return (b & 0x80000000u) ? ~b : (b | 0x80000000u);
}
__device__ __forceinline__ float funkey(unsigned k) {
    unsigned b = (k & 0x80000000u) ? (k ^ 0x80000000u) : ~k;
    return __uint_as_float(b);
}

// h = relu(x @ encW + encb), x:[NN,64], W:[64,128]
__global__ __launch_bounds__(256) void encoder_kernel(const float* __restrict__ x,
    const float* __restrict__ W, const float* __restrict__ b, float* __restrict__ h)
{
    const int tid = threadIdx.x, q = tid & 31, no = tid >> 5;
    const int nbase = blockIdx.x * 64;
    float4 bv = ld4(b + 4 * q);
    float4 acc[8];
#pragma unroll
    for (int i = 0; i < 8; ++i) acc[i] = bv;
    for (int k4 = 0; k4 < 16; ++k4) {
        const float* wp = W + (4 * k4) * H + 4 * q;
        float4 w0 = ld4(wp), w1 = ld4(wp + H), w2 = ld4(wp + 2 * H), w3 = ld4(wp + 3 * H);
#pragma unroll
        for (int i = 0; i < 8; ++i) {
            int n = nbase + no * 8 + i; n = n < NN ? n : NN - 1;
            float4 a = ld4(x + n * DIN + 4 * k4);
            fma4(acc[i], a.x, w0); fma4(acc[i], a.y, w1);
            fma4(acc[i], a.z, w2); fma4(acc[i], a.w, w3);
        }
    }
#pragma unroll
    for (int i = 0; i < 8; ++i) {
        int n = nbase + no * 8 + i;
        if (n < NN) st4(h + n * H + 4 * q, relu4(acc[i]));
    }
}

__global__ __launch_bounds__(256) void dist2_kernel(const float* __restrict__ pos,
    const int* __restrict__ ei, float* __restrict__ d2)
{
    int e = blockIdx.x * 256 + threadIdx.x;
    if (e >= NE) return;
    int s = ei[e], d = ei[NE + e];
    float dx = pos[s * 3 + 0] - pos[d * 3 + 0];
    float dy = pos[s * 3 + 1] - pos[d * 3 + 1];
    float dz = pos[s * 3 + 2] - pos[d * 3 + 2];
    d2[e] = dx * dx + dy * dy + dz * dz;
}

// ---------- counting sort of edges by dst ----------
__global__ __launch_bounds__(256) void hist_kernel(const int* __restrict__ ei, int* __restrict__ deg)
{
    int e = blockIdx.x * 256 + threadIdx.x;
    if (e < NE) atomicAdd(&deg[ei[NE + e]], 1);
}

// single block, 256 threads: exclusive scan of deg[NN] -> cursor
__global__ __launch_bounds__(256) void scan_kernel(const int* __restrict__ deg, int* __restrict__ cursor)
{
    __shared__ int tot[256];
    const int t = threadIdx.x;
    const int CH = (NN + 255) / 256;  // 196
    const int base = t * CH;
    int s = 0;
    for (int i = 0; i < CH; ++i) {
        int idx = base + i;
        if (idx < NN) s += deg[idx];
    }
    tot[t] = s;
    __syncthreads();
    for (int off = 1; off < 256; off <<= 1) {
        int v = (t >= off) ? tot[t - off] : 0;
        __syncthreads();
        tot[t] += v;
        __syncthreads();
    }
    int run = (t == 0) ? 0 : tot[t - 1];
    for (int i = 0; i < CH; ++i) {
        int idx = base + i;
        if (idx < NN) { cursor[idx] = run; run += deg[idx]; }
    }
}

__global__ __launch_bounds__(256) void scatter_kernel(const int* __restrict__ ei,
    const float* __restrict__ ea, const float* __restrict__ d2, int* __restrict__ cursor,
    int* __restrict__ src_s, int* __restrict__ dst_s,
    float* __restrict__ ea_s, float* __restrict__ d2_s)
{
    int e = blockIdx.x * 256 + threadIdx.x;
    if (e >= NE) return;
    int s = ei[e], d = ei[NE + e];
    int pos = atomicAdd(&cursor[d], 1);
    src_s[pos] = s; dst_s[pos] = d; d2_s[pos] = d2[e];
    const float4* ev = reinterpret_cast<const float4*>(ea + (size_t)e * DEA);
    float4* ov = reinterpret_cast<float4*>(ea_s + (size_t)pos * DEA);
    ov[0] = ev[0]; ov[1] = ev[1]; ov[2] = ev[2]; ov[3] = ev[3];
}

// Pd = h @ W1[0:128], Ps = h @ W1[128:256]   (W1 = eW1[l], [273][128])
__global__ __launch_bounds__(256) void proj_kernel(const float* __restrict__ h,
    const float* __restrict__ W1, float* __restrict__ Pd, float* __restrict__ Ps)
{
    const int tid = threadIdx.x, q = tid & 31, no = tid >> 5;
    const int nbase = blockIdx.x * 64;
    float4 ad[8], as[8];
#pragma unroll
    for (int i = 0; i < 8; ++i) { ad[i] = make_float4(0, 0, 0, 0); as[i] = make_float4(0, 0, 0, 0); }
    for (int k4 = 0; k4 < 32; ++k4) {
        const float* wdp = W1 + (4 * k4) * H + 4 * q;
        const float* wsp = W1 + (128 + 4 * k4) * H + 4 * q;
        float4 wd0 = ld4(wdp), wd1 = ld4(wdp + H), wd2 = ld4(wdp + 2 * H), wd3 = ld4(wdp + 3 * H);
        float4 ws0 = ld4(wsp), ws1 = ld4(wsp + H), ws2 = ld4(wsp + 2 * H), ws3 = ld4(wsp + 3 * H);
#pragma unroll
        for (int i = 0; i < 8; ++i) {
            int n = nbase + no * 8 + i; n = n < NN ? n : NN - 1;
            float4 a = ld4(h + n * H + 4 * k4);
            fma4(ad[i], a.x, wd0); fma4(ad[i], a.y, wd1); fma4(ad[i], a.z, wd2); fma4(ad[i], a.w, wd3);
            fma4(as[i], a.x, ws0); fma4(as[i], a.y, ws1); fma4(as[i], a.z, ws2); fma4(as[i], a.w, ws3);
        }
    }
#pragma unroll
    for (int i = 0; i < 8; ++i) {
        int n = nbase + no * 8 + i;
        if (n < NN) { st4(Pd + n * H + 4 * q, ad[i]); st4(Ps + n * H + 4 * q, as[i]); }
    }
}

__device__ __forceinline__ void flush_run(float* __restrict__ agg, int d, int q, float4 v)
{
    float* ap = agg + (size_t)d * H + 4 * q;
    atomicAdd(ap + 0, v.x); atomicAdd(ap + 1, v.y);
    atomicAdd(ap + 2, v.z); atomicAdd(ap + 3, v.w);
}

// dst-sorted edges: t = relu(Pd[dst]+Ps[src]+ea@Wea+d2*wd+b1); m = relu(t@W2+b2);
// segmented-reduce m over dst runs, one atomic flush per run
__global__ __launch_bounds__(256) void edge_sorted_kernel(
    const float* __restrict__ Pd, const float* __restrict__ Ps,
    const float* __restrict__ ea_s, const float* __restrict__ d2_s,
    const int* __restrict__ src_s, const int* __restrict__ dst_s,
    const float* __restrict__ W1, const float* __restrict__ b1,
    const float* __restrict__ W2, const float* __restrict__ b2,
    float* __restrict__ agg)
{
    __shared__ float tls[64 * H];
    const int tid = threadIdx.x, q = tid & 31, eo = tid >> 5;
    const int ebase = blockIdx.x * 64;
    int dsts[8];
    const float* Wea = W1 + 256 * H;
    const float* wdv = W1 + 272 * H;
    float4 b1v = ld4(b1 + 4 * q);
    float4 wdq = ld4(wdv + 4 * q);
#pragma unroll
    for (int i = 0; i < 8; ++i) {
        int el = eo * 8 + i, j = ebase + el;
        int s = src_s[j], d = dst_s[j];
        dsts[i] = d;
        float4 acc = f4add(ld4(Pd + (size_t)d * H + 4 * q), ld4(Ps + (size_t)s * H + 4 * q));
        acc = f4add(acc, b1v);
        fma4(acc, d2_s[j], wdq);
        const float4* eav = reinterpret_cast<const float4*>(ea_s + (size_t)j * DEA);
#pragma unroll
        for (int k4 = 0; k4 < 4; ++k4) {
            float4 av = eav[k4];
            fma4(acc, av.x, ld4(Wea + (4 * k4 + 0) * H + 4 * q));
            fma4(acc, av.y, ld4(Wea + (4 * k4 + 1) * H + 4 * q));
            fma4(acc, av.z, ld4(Wea + (4 * k4 + 2) * H + 4 * q));
            fma4(acc, av.w, ld4(Wea + (4 * k4 + 3) * H + 4 * q));
        }
        st4(&tls[el * H + 4 * q], relu4(acc));
    }
    __syncthreads();
    float4 b2v = ld4(b2 + 4 * q);
    float4 acc[8];
#pragma unroll
    for (int i = 0; i < 8; ++i) acc[i] = b2v;
    for (int k4 = 0; k4 < 32; ++k4) {
        const float* wp = W2 + (4 * k4) * H + 4 * q;
        float4 w0 = ld4(wp), w1 = ld4(wp + H), w2 = ld4(wp + 2 * H), w3 = ld4(wp + 3 * H);
#pragma unroll
        for (int i = 0; i < 8; ++i) {
            float4 t = *reinterpret_cast<const float4*>(&tls[(eo * 8 + i) * H + 4 * k4]);
            fma4(acc[i], t.x, w0); fma4(acc[i], t.y, w1);
            fma4(acc[i], t.z, w2); fma4(acc[i], t.w, w3);
        }
    }
    // segmented reduction over dst runs (edges are dst-sorted)
    float4 run = relu4(acc[0]);
    int rd = dsts[0];
#pragma unroll
    for (int i = 1; i < 8; ++i) {
        float4 m = relu4(acc[i]);
        if (dsts[i] == rd) { run = f4add(run, m); }
        else { flush_run(agg, rd, q, run); rd = dsts[i]; run = m; }
    }
    flush_run(agg, rd, q, run);
}

// h' = relu([h,agg] @ nW1 + nb1) @ nW2 + nb2   (no final relu)
__global__ __launch_bounds__(256) void node_kernel(
    const float* __restrict__ h, const float* __restrict__ agg,
    const float* __restrict__ W1, const float* __restrict__ b1,
    const float* __restrict__ W2, const float* __restrict__ b2,
    float* __restrict__ hout)
{
    __shared__ float uls[64 * H];
    const int tid = threadIdx.x, q = tid & 31, no = tid >> 5;
    const int nbase = blockIdx.x * 64;
    float4 acc[8];
    float4 b1v = ld4(b1 + 4 * q);
#pragma unroll
    for (int i = 0; i < 8; ++i) acc[i] = b1v;
    for (int k4 = 0; k4 < 32; ++k4) {
        const float* wp = W1 + (4 * k4) * H + 4 * q;
        float4 w0 = ld4(wp), w1 = ld4(wp + H), w2 = ld4(wp + 2 * H), w3 = ld4(wp + 3 * H);
#pragma unroll
        for (int i = 0; i < 8; ++i) {
            int n = nbase + no * 8 + i; n = n < NN ? n : NN - 1;
            float4 a = ld4(h + n * H + 4 * k4);
            fma4(acc[i], a.x, w0); fma4(acc[i], a.y, w1);
            fma4(acc[i], a.z, w2); fma4(acc[i], a.w, w3);
        }
    }
    for (int k4 = 0; k4 < 32; ++k4) {
        const float* wp = W1 + (128 + 4 * k4) * H + 4 * q;
        float4 w0 = ld4(wp), w1 = ld4(wp + H), w2 = ld4(wp + 2 * H), w3 = ld4(wp + 3 * H);
#pragma unroll
        for (int i = 0; i < 8; ++i) {
            int n = nbase + no * 8 + i; n = n < NN ? n : NN - 1;
            float4 a = ld4(agg + n * H + 4 * k4);
            fma4(acc[i], a.x, w0); fma4(acc[i], a.y, w1);
            fma4(acc[i], a.z, w2); fma4(acc[i], a.w, w3);
        }
    }
#pragma unroll
    for (int i = 0; i < 8; ++i) st4(&uls[(no * 8 + i) * H + 4 * q], relu4(acc[i]));
    __syncthreads();
    float4 acc2[8];
    float4 b2v = ld4(b2 + 4 * q);
#pragma unroll
    for (int i = 0; i < 8; ++i) acc2[i] = b2v;
    for (int k4 = 0; k4 < 32; ++k4) {
        const float* wp = W2 + (4 * k4) * H + 4 * q;
        float4 w0 = ld4(wp), w1 = ld4(wp + H), w2 = ld4(wp + 2 * H), w3 = ld4(wp + 3 * H);
#pragma unroll
        for (int i = 0; i < 8; ++i) {
            float4 t = *reinterpret_cast<const float4*>(&uls[(no * 8 + i) * H + 4 * k4]);
            fma4(acc2[i], t.x, w0); fma4(acc2[i], t.y, w1);
            fma4(acc2[i], t.z, w2); fma4(acc2[i], t.w, w3);
        }
    }
#pragma unroll
    for (int i = 0; i < 8; ++i) {
        int n = nbase + no * 8 + i;
        if (n < NN) st4(hout + n * H + 4 * q, acc2[i]);  // NO relu on final
    }
}

// batch is sorted: run-length local reduce then one atomic per run
__global__ __launch_bounds__(256) void pool_kernel(const float* __restrict__ h,
    const int* __restrict__ batch, float* __restrict__ ssum,
    unsigned int* __restrict__ smaxk, float* __restrict__ cnt)
{
    const int tid = threadIdx.x, j = tid & 127, half = tid >> 7;
    const int nbase = blockIdx.x * 64;
    int cur = -1, rc = 0;
    float s = 0.f, mx = 0.f;
    for (int i = 0; i < 32; ++i) {
        int n = nbase + 2 * i + half;
        if (n >= NN) break;
        int g = batch[n];
        float v = h[(size_t)n * H + j];
        if (g != cur) {
            if (cur >= 0) {
                atomicAdd(&ssum[cur * H + j], s);
                atomicMax(&smaxk[cur * H + j], fkey(mx));
                if (j == 0) atomicAdd(&cnt[cur], (float)rc);
            }
            cur = g; s = v; mx = v; rc = 1;
        } else { s += v; mx = fmaxf(mx, v); rc++; }
    }
    if (cur >= 0) {
        atomicAdd(&ssum[cur * H + j], s);
        atomicMax(&smaxk[cur * H + j], fkey(mx));
        if (j == 0) atomicAdd(&cnt[cur], (float)rc);
    }
}

__global__ __launch_bounds__(128) void readout_kernel(const float* __restrict__ ssum,
    const unsigned int* __restrict__ smaxk, const float* __restrict__ cnt,
    const float* __restrict__ rW1, const float* __restrict__ rb1,
    const float* __restrict__ rW2, const float* __restrict__ rb2,
    const float* __restrict__ rW3, const float* __restrict__ rb3,
    float* __restrict__ out)
{
    __shared__ float p[384], h1[128], h2[64];
    const int g = blockIdx.x, j = threadIdx.x;
    float c = fmaxf(cnt[g], 1.0f);
    float sv = ssum[g * H + j];
    p[j] = sv / c;
    p[128 + j] = funkey(smaxk[g * H + j]);
    p[256 + j] = sv;
    __syncthreads();
    float a = rb1[j];
    for (int k = 0; k < 384; ++k) a = fmaf(p[k], rW1[k * H + j], a);
    h1[j] = fmaxf(a, 0.f);
    __syncthreads();
    if (j < 64) {
        float a2 = rb2[j];
        for (int k = 0; k < 128; ++k) a2 = fmaf(h1[k], rW2[k * 64 + j], a2);
        h2[j] = fmaxf(a2, 0.f);
    }
    __syncthreads();
    if (j < 64) {
        float t = h2[j] * rW3[j];
        for (int off = 32; off; off >>= 1) t += __shfl_down(t, off);
        if (j == 0) {
            float z = t + rb3[0];
            out[g] = z > 20.f ? z : log1pf(expf(z));
        }
    }
}

extern "C" void kernel_launch(void* const* d_in, const int* in_sizes, int n_in,
                              void* d_out, int out_size, void* d_ws, size_t ws_size,
                              hipStream_t stream)
{
    const float* x    = (const float*)d_in[0];
    const float* pos  = (const float*)d_in[1];
    const float* ea   = (const float*)d_in[2];
    const int*   ei   = (const int*)d_in[3];
    const int*   batch= (const int*)d_in[4];
    const float* encW = (const float*)d_in[5];
    const float* encb = (const float*)d_in[6];
    const float* eW1  = (const float*)d_in[7];
    const float* eb1  = (const float*)d_in[8];
    const float* eW2  = (const float*)d_in[9];
    const float* eb2  = (const float*)d_in[10];
    const float* nW1  = (const float*)d_in[11];
    const float* nb1  = (const float*)d_in[12];
    const float* nW2  = (const float*)d_in[13];
    const float* nb2  = (const float*)d_in[14];
    const float* rW1  = (const float*)d_in[15];
    const float* rb1  = (const float*)d_in[16];
    const float* rW2  = (const float*)d_in[17];
    const float* rb2  = (const float*)d_in[18];
    const float* rW3  = (const float*)d_in[19];
    const float* rb3  = (const float*)d_in[20];

    char* w = (char*)d_ws;
    size_t o = 0;
    auto alloc = [&](size_t bytes) -> char* {
        char* p = w + o; o += (bytes + 255) / 256 * 256; return p;
    };
    float* hA   = (float*)alloc((size_t)NN * H * 4);
    float* hB   = (float*)alloc((size_t)NN * H * 4);
    float* Pd   = (float*)alloc((size_t)NN * H * 4);
    float* Ps   = (float*)alloc((size_t)NN * H * 4);
    float* agg  = (float*)alloc((size_t)NN * H * 4);
    float* d2   = (float*)alloc((size_t)NE * 4);
    float* ssum = (float*)alloc((size_t)NG * H * 4);
    unsigned int* smaxk = (unsigned int*)alloc((size_t)NG * H * 4);
    float* cnt  = (float*)alloc((size_t)NG * 4);
    // sort scratch
    int*   deg    = (int*)alloc((size_t)NN * 4);
    int*   cursor = (int*)alloc((size_t)NN * 4);
    int*   src_s  = (int*)alloc((size_t)NE * 4);
    int*   dst_s  = (int*)alloc((size_t)NE * 4);
    float* ea_s   = (float*)alloc((size_t)NE * DEA * 4);
    float* d2_s   = (float*)alloc((size_t)NE * 4);
    (void)ws_size; (void)in_sizes; (void)n_in; (void)out_size;

    const int NB = (NN + 63) / 64;
    const int EB = (NE + 255) / 256;

    // build dst-sorted edge arrays (counting sort), once per call
    hipMemsetAsync(deg, 0, (size_t)NN * 4, stream);
    dist2_kernel<<<EB, 256, 0, stream>>>(pos, ei, d2);
    hist_kernel<<<EB, 256, 0, stream>>>(ei, deg);
    scan_kernel<<<1, 256, 0, stream>>>(deg, cursor);
    scatter_kernel<<<EB, 256, 0, stream>>>(ei, ea, d2, cursor, src_s, dst_s, ea_s, d2_s);

    encoder_kernel<<<NB, 256, 0, stream>>>(x, encW, encb, hA);

    float* hcur = hA;
    float* hnext = hB;
    for (int l = 0; l < NL; ++l) {
        hipMemsetAsync(agg, 0, (size_t)NN * H * 4, stream);
        const float* W1 = eW1 + (size_t)l * 273 * H;
        proj_kernel<<<NB, 256, 0, stream>>>(hcur, W1, Pd, Ps);
        edge_sorted_kernel<<<NE / 64, 256, 0, stream>>>(Pd, Ps, ea_s, d2_s, src_s, dst_s,
            W1, eb1 + l * H, eW2 + (size_t)l * H * H, eb2 + l * H, agg);
        node_kernel<<<NB, 256, 0, stream>>>(hcur, agg,
            nW1 + (size_t)l * 256 * H, nb1 + l * H, nW2 + (size_t)l * H * H, nb2 + l * H, hnext);
        float* tmp = hcur; hcur = hnext; hnext = tmp;
    }

    hipMemsetAsync(ssum, 0, (size_t)NG * H * 4, stream);
    hipMemsetAsync(smaxk, 0, (size_t)NG * H * 4, stream);
    hipMemsetAsync(cnt, 0, (size_t)NG * 4, stream);
    pool_kernel<<<NB, 256, 0, stream>>>(hcur, batch, ssum, smaxk, cnt);
    readout_kernel<<<NG, 128, 0, stream>>>(ssum, smaxk, cnt,
        rW1, rb1, rW2, rb2, rW3, rb3, (float*)d_out);
}

// Round 3
// 2999.382 us; speedup vs baseline: 2.8824x; 2.3211x over previous
//
#include <hip/hip_runtime.h>
#include <math.h>

#define NN 50000
#define NE 800000
#define NG 64
#define DIN 64
#define DEA 16
#define H 128
#define NL 4
#define EPB 128   // edges per block in edge_mfma_kernel

typedef __attribute__((ext_vector_type(8))) short short8;
typedef __attribute__((ext_vector_type(4))) float f32x4;

__device__ __forceinline__ float4 ld4(const float* p) { return *reinterpret_cast<const float4*>(p); }
__device__ __forceinline__ void st4(float* p, float4 v) { *reinterpret_cast<float4*>(p) = v; }
__device__ __forceinline__ void fma4(float4& a, float s, float4 w) {
    a.x = fmaf(s, w.x, a.x); a.y = fmaf(s, w.y, a.y);
    a.z = fmaf(s, w.z, a.z); a.w = fmaf(s, w.w, a.w);
}
__device__ __forceinline__ float4 f4add(float4 a, float4 b) {
    return make_float4(a.x + b.x, a.y + b.y, a.z + b.z, a.w + b.w);
}
__device__ __forceinline__ float4 relu4(float4 a) {
    return make_float4(fmaxf(a.x, 0.f), fmaxf(a.y, 0.f), fmaxf(a.z, 0.f), fmaxf(a.w, 0.f));
}
__device__ __forceinline__ unsigned fkey(float f) {
    unsigned b = __float_as_uint(f);
    return (b & 0x80000000u) ? ~b : (b | 0x80000000u);
}
__device__ __forceinline__ float funkey(unsigned k) {
    unsigned b = (k & 0x80000000u) ? (k ^ 0x80000000u) : ~k;
    return __uint_as_float(b);
}
__device__ __forceinline__ ushort f2bf(float f) {
    unsigned u = __float_as_uint(f);
    return (ushort)((u + 0x7fffu + ((u >> 16) & 1u)) >> 16);
}
__device__ __forceinline__ float bf2f(ushort b) {
    return __uint_as_float(((unsigned)b) << 16);
}

// h = relu(x @ encW + encb), x:[NN,64], W:[64,128]
__global__ __launch_bounds__(256) void encoder_kernel(const float* __restrict__ x,
    const float* __restrict__ W, const float* __restrict__ b, float* __restrict__ h)
{
    const int tid = threadIdx.x, q = tid & 31, no = tid >> 5;
    const int nbase = blockIdx.x * 64;
    float4 bv = ld4(b + 4 * q);
    float4 acc[8];
#pragma unroll
    for (int i = 0; i < 8; ++i) acc[i] = bv;
    for (int k4 = 0; k4 < 16; ++k4) {
        const float* wp = W + (4 * k4) * H + 4 * q;
        float4 w0 = ld4(wp), w1 = ld4(wp + H), w2 = ld4(wp + 2 * H), w3 = ld4(wp + 3 * H);
#pragma unroll
        for (int i = 0; i < 8; ++i) {
            int n = nbase + no * 8 + i; n = n < NN ? n : NN - 1;
            float4 a = ld4(x + n * DIN + 4 * k4);
            fma4(acc[i], a.x, w0); fma4(acc[i], a.y, w1);
            fma4(acc[i], a.z, w2); fma4(acc[i], a.w, w3);
        }
    }
#pragma unroll
    for (int i = 0; i < 8; ++i) {
        int n = nbase + no * 8 + i;
        if (n < NN) st4(h + n * H + 4 * q, relu4(acc[i]));
    }
}

__global__ __launch_bounds__(256) void dist2_kernel(const float* __restrict__ pos,
    const int* __restrict__ ei, float* __restrict__ d2)
{
    int e = blockIdx.x * 256 + threadIdx.x;
    if (e >= NE) return;
    int s = ei[e], d = ei[NE + e];
    float dx = pos[s * 3 + 0] - pos[d * 3 + 0];
    float dy = pos[s * 3 + 1] - pos[d * 3 + 1];
    float dz = pos[s * 3 + 2] - pos[d * 3 + 2];
    d2[e] = dx * dx + dy * dy + dz * dz;
}

// ---------- counting sort of edges by dst ----------
__global__ __launch_bounds__(256) void hist_kernel(const int* __restrict__ ei, int* __restrict__ deg)
{
    int e = blockIdx.x * 256 + threadIdx.x;
    if (e < NE) atomicAdd(&deg[ei[NE + e]], 1);
}

__global__ __launch_bounds__(256) void scan_kernel(const int* __restrict__ deg, int* __restrict__ cursor)
{
    __shared__ int tot[256];
    const int t = threadIdx.x;
    const int CH = (NN + 255) / 256;
    const int base = t * CH;
    int s = 0;
    for (int i = 0; i < CH; ++i) {
        int idx = base + i;
        if (idx < NN) s += deg[idx];
    }
    tot[t] = s;
    __syncthreads();
    for (int off = 1; off < 256; off <<= 1) {
        int v = (t >= off) ? tot[t - off] : 0;
        __syncthreads();
        tot[t] += v;
        __syncthreads();
    }
    int run = (t == 0) ? 0 : tot[t - 1];
    for (int i = 0; i < CH; ++i) {
        int idx = base + i;
        if (idx < NN) { cursor[idx] = run; run += deg[idx]; }
    }
}

__global__ __launch_bounds__(256) void scatter_kernel(const int* __restrict__ ei,
    const float* __restrict__ ea, const float* __restrict__ d2, int* __restrict__ cursor,
    int* __restrict__ src_s, int* __restrict__ dst_s,
    float* __restrict__ ea_s, float* __restrict__ d2_s)
{
    int e = blockIdx.x * 256 + threadIdx.x;
    if (e >= NE) return;
    int s = ei[e], d = ei[NE + e];
    int pos = atomicAdd(&cursor[d], 1);
    src_s[pos] = s; dst_s[pos] = d; d2_s[pos] = d2[e];
    const float4* ev = reinterpret_cast<const float4*>(ea + (size_t)e * DEA);
    float4* ov = reinterpret_cast<float4*>(ea_s + (size_t)pos * DEA);
    ov[0] = ev[0]; ov[1] = ev[1]; ov[2] = ev[2]; ov[3] = ev[3];
}

// ---------- per-layer W2 -> split bf16 (hi+lo), transposed [n][k], swizzled ----------
// dest layout (ushort units, per layer 16384): pos = half*8192 + n*64 + (kk ^ ((n&7)<<3)), kk=k&63
__global__ __launch_bounds__(256) void w2prep_kernel(const float* __restrict__ eW2,
    ushort* __restrict__ hi, ushort* __restrict__ lo)
{
    int l = blockIdx.x;
    const float* W = eW2 + (size_t)l * H * H;
    ushort* hg = hi + (size_t)l * H * H;
    ushort* lg = lo + (size_t)l * H * H;
    for (int idx = threadIdx.x; idx < H * H; idx += 256) {
        int k = idx >> 7, n = idx & 127;
        float wv = W[idx];
        ushort hb = f2bf(wv);
        float rem = wv - bf2f(hb);
        ushort lb = f2bf(rem);
        int half = k >> 6, kk = k & 63;
        int pos = (half << 13) + (n << 6) + (kk ^ ((n & 7) << 3));
        hg[pos] = hb; lg[pos] = lb;
    }
}

// Pd = h @ W1[0:128], Ps = h @ W1[128:256]
__global__ __launch_bounds__(256) void proj_kernel(const float* __restrict__ h,
    const float* __restrict__ W1, float* __restrict__ Pd, float* __restrict__ Ps)
{
    const int tid = threadIdx.x, q = tid & 31, no = tid >> 5;
    const int nbase = blockIdx.x * 64;
    float4 ad[8], as[8];
#pragma unroll
    for (int i = 0; i < 8; ++i) { ad[i] = make_float4(0, 0, 0, 0); as[i] = make_float4(0, 0, 0, 0); }
    for (int k4 = 0; k4 < 32; ++k4) {
        const float* wdp = W1 + (4 * k4) * H + 4 * q;
        const float* wsp = W1 + (128 + 4 * k4) * H + 4 * q;
        float4 wd0 = ld4(wdp), wd1 = ld4(wdp + H), wd2 = ld4(wdp + 2 * H), wd3 = ld4(wdp + 3 * H);
        float4 ws0 = ld4(wsp), ws1 = ld4(wsp + H), ws2 = ld4(wsp + 2 * H), ws3 = ld4(wsp + 3 * H);
#pragma unroll
        for (int i = 0; i < 8; ++i) {
            int n = nbase + no * 8 + i; n = n < NN ? n : NN - 1;
            float4 a = ld4(h + n * H + 4 * k4);
            fma4(ad[i], a.x, wd0); fma4(ad[i], a.y, wd1); fma4(ad[i], a.z, wd2); fma4(ad[i], a.w, wd3);
            fma4(as[i], a.x, ws0); fma4(as[i], a.y, ws1); fma4(as[i], a.z, ws2); fma4(as[i], a.w, ws3);
        }
    }
#pragma unroll
    for (int i = 0; i < 8; ++i) {
        int n = nbase + no * 8 + i;
        if (n < NN) { st4(Pd + n * H + 4 * q, ad[i]); st4(Ps + n * H + 4 * q, as[i]); }
    }
}

// dst-sorted edges, 128 edges/block, 8 waves.
// stage1 (fp32 VALU): t = relu(Pd[dst]+Ps[src]+ea@Wea+d2*wd+b1) -> bf16 swizzled LDS
// stage2 (MFMA bf16): m = relu(t @ (W2hi+W2lo) + b2), segmented atomic flush to agg
__global__ __launch_bounds__(512, 4) void edge_mfma_kernel(
    const float* __restrict__ Pd, const float* __restrict__ Ps,
    const float* __restrict__ ea_s, const float* __restrict__ d2_s,
    const int* __restrict__ src_s, const int* __restrict__ dst_s,
    const float* __restrict__ W1, const float* __restrict__ b1,
    const ushort* __restrict__ w2hiL, const ushort* __restrict__ w2loL,
    const float* __restrict__ b2, float* __restrict__ agg)
{
    __shared__ __align__(16) ushort tls[EPB * H];   // 32KB: t bf16, swizzled rows
    __shared__ __align__(16) ushort whi[H * 64];    // 16KB: W2hi^T k-half, swizzled
    __shared__ __align__(16) ushort wlo[H * 64];    // 16KB

    const int tid = threadIdx.x, q = tid & 31, eo = tid >> 5;   // eo in [0,16)
    const int ebase = blockIdx.x * EPB;

    // prefetch W k-half 0 (hi+lo) into regs; pre-swizzled in global, linear copy
    const int4* ghi = (const int4*)w2hiL;
    const int4* glo = (const int4*)w2loL;
    int4 rh0[2], rl0[2];
    rh0[0] = ghi[tid]; rh0[1] = ghi[tid + 512];
    rl0[0] = glo[tid]; rl0[1] = glo[tid + 512];

    // ---- stage 1: edge MLP layer-1 (fp32) ----
    const float* Wea = W1 + 256 * H;
    const float* wdv = W1 + 272 * H;
    float4 b1v = ld4(b1 + 4 * q);
    float4 wdq = ld4(wdv + 4 * q);
    int dlast = -1;
    float4 pdv = make_float4(0, 0, 0, 0);
#pragma unroll
    for (int i = 0; i < 8; ++i) {
        int el = eo * 8 + i, j = ebase + el;
        int s = src_s[j], d = dst_s[j];
        if (d != dlast) { pdv = ld4(Pd + (size_t)d * H + 4 * q); dlast = d; }
        float4 acc = f4add(pdv, ld4(Ps + (size_t)s * H + 4 * q));
        acc = f4add(acc, b1v);
        fma4(acc, d2_s[j], wdq);
        const float4* eav = reinterpret_cast<const float4*>(ea_s + (size_t)j * DEA);
#pragma unroll
        for (int k4 = 0; k4 < 4; ++k4) {
            float4 av = eav[k4];
            fma4(acc, av.x, ld4(Wea + (4 * k4 + 0) * H + 4 * q));
            fma4(acc, av.y, ld4(Wea + (4 * k4 + 1) * H + 4 * q));
            fma4(acc, av.z, ld4(Wea + (4 * k4 + 2) * H + 4 * q));
            fma4(acc, av.w, ld4(Wea + (4 * k4 + 3) * H + 4 * q));
        }
        // relu + bf16 + swizzled store (8B)
        ushort4 tv;
        tv.x = f2bf(fmaxf(acc.x, 0.f)); tv.y = f2bf(fmaxf(acc.y, 0.f));
        tv.z = f2bf(fmaxf(acc.z, 0.f)); tv.w = f2bf(fmaxf(acc.w, 0.f));
        int tidx = el * H + ((4 * q) ^ ((el & 7) << 3));
        *reinterpret_cast<ushort4*>(&tls[tidx]) = tv;
    }

    // write W half0 to LDS, prefetch half1
    ((int4*)whi)[tid] = rh0[0]; ((int4*)whi)[tid + 512] = rh0[1];
    ((int4*)wlo)[tid] = rl0[0]; ((int4*)wlo)[tid + 512] = rl0[1];
    int4 rh1[2], rl1[2];
    rh1[0] = ghi[1024 + tid]; rh1[1] = ghi[1024 + tid + 512];
    rl1[0] = glo[1024 + tid]; rl1[1] = glo[1024 + tid + 512];
    __syncthreads();

    // ---- stage 2: MFMA t @ W2 ----
    const int lane = tid & 63, wv = tid >> 6;   // 8 waves x 16 rows
    const int col = lane & 15, g = lane >> 4;
    f32x4 acc[8];
#pragma unroll
    for (int nt = 0; nt < 8; ++nt) {
        float bb = b2[nt * 16 + col];
        acc[nt] = (f32x4){bb, bb, bb, bb};
    }
    const int arow = wv * 16 + col;
    const int aswz = (arow & 7) << 3;

#define KSTEP(k0, kk0)                                                            \
    {                                                                             \
        short8 af = *(const short8*)&tls[arow * H + (((k0) + 8 * g) ^ aswz)];     \
        _Pragma("unroll")                                                         \
        for (int nt = 0; nt < 8; ++nt) {                                          \
            int brow = nt * 16 + col;                                             \
            int bidx = brow * 64 + (((kk0) + 8 * g) ^ ((brow & 7) << 3));         \
            short8 bh = *(const short8*)&whi[bidx];                               \
            short8 bl = *(const short8*)&wlo[bidx];                               \
            acc[nt] = __builtin_amdgcn_mfma_f32_16x16x32_bf16(af, bh, acc[nt], 0, 0, 0); \
            acc[nt] = __builtin_amdgcn_mfma_f32_16x16x32_bf16(af, bl, acc[nt], 0, 0, 0); \
        }                                                                         \
    }

    KSTEP(0, 0)
    KSTEP(32, 32)
    __syncthreads();
    ((int4*)whi)[tid] = rh1[0]; ((int4*)whi)[tid + 512] = rh1[1];
    ((int4*)wlo)[tid] = rl1[0]; ((int4*)wlo)[tid + 512] = rl1[1];
    __syncthreads();
    KSTEP(64, 0)
    KSTEP(96, 32)
#undef KSTEP

    // ---- flush: C frag rows = edges (row=(lane>>4)*4+reg), cols = nt*16 + (lane&15) ----
    const int growbase = ebase + wv * 16 + g * 4;
    int dr[4];
#pragma unroll
    for (int r = 0; r < 4; ++r) dr[r] = dst_s[growbase + r];
    float vrun[8];
    int dcur = dr[0];
#pragma unroll
    for (int nt = 0; nt < 8; ++nt) vrun[nt] = fmaxf(acc[nt][0], 0.f);
#pragma unroll
    for (int r = 1; r < 4; ++r) {
        if (dr[r] != dcur) {
#pragma unroll
            for (int nt = 0; nt < 8; ++nt) {
                atomicAdd(&agg[(size_t)dcur * H + nt * 16 + col], vrun[nt]);
                vrun[nt] = fmaxf(acc[nt][r], 0.f);
            }
            dcur = dr[r];
        } else {
#pragma unroll
            for (int nt = 0; nt < 8; ++nt) vrun[nt] += fmaxf(acc[nt][r], 0.f);
        }
    }
#pragma unroll
    for (int nt = 0; nt < 8; ++nt)
        atomicAdd(&agg[(size_t)dcur * H + nt * 16 + col], vrun[nt]);
}

// h' = relu([h,agg] @ nW1 + nb1) @ nW2 + nb2   (no final relu)
__global__ __launch_bounds__(256) void node_kernel(
    const float* __restrict__ h, const float* __restrict__ agg,
    const float* __restrict__ W1, const float* __restrict__ b1,
    const float* __restrict__ W2, const float* __restrict__ b2,
    float* __restrict__ hout)
{
    __shared__ float uls[64 * H];
    const int tid = threadIdx.x, q = tid & 31, no = tid >> 5;
    const int nbase = blockIdx.x * 64;
    float4 acc[8];
    float4 b1v = ld4(b1 + 4 * q);
#pragma unroll
    for (int i = 0; i < 8; ++i) acc[i] = b1v;
    for (int k4 = 0; k4 < 32; ++k4) {
        const float* wp = W1 + (4 * k4) * H + 4 * q;
        float4 w0 = ld4(wp), w1 = ld4(wp + H), w2 = ld4(wp + 2 * H), w3 = ld4(wp + 3 * H);
#pragma unroll
        for (int i = 0; i < 8; ++i) {
            int n = nbase + no * 8 + i; n = n < NN ? n : NN - 1;
            float4 a = ld4(h + n * H + 4 * k4);
            fma4(acc[i], a.x, w0); fma4(acc[i], a.y, w1);
            fma4(acc[i], a.z, w2); fma4(acc[i], a.w, w3);
        }
    }
    for (int k4 = 0; k4 < 32; ++k4) {
        const float* wp = W1 + (128 + 4 * k4) * H + 4 * q;
        float4 w0 = ld4(wp), w1 = ld4(wp + H), w2 = ld4(wp + 2 * H), w3 = ld4(wp + 3 * H);
#pragma unroll
        for (int i = 0; i < 8; ++i) {
            int n = nbase + no * 8 + i; n = n < NN ? n : NN - 1;
            float4 a = ld4(agg + n * H + 4 * k4);
            fma4(acc[i], a.x, w0); fma4(acc[i], a.y, w1);
            fma4(acc[i], a.z, w2); fma4(acc[i], a.w, w3);
        }
    }
#pragma unroll
    for (int i = 0; i < 8; ++i) st4(&uls[(no * 8 + i) * H + 4 * q], relu4(acc[i]));
    __syncthreads();
    float4 acc2[8];
    float4 b2v = ld4(b2 + 4 * q);
#pragma unroll
    for (int i = 0; i < 8; ++i) acc2[i] = b2v;
    for (int k4 = 0; k4 < 32; ++k4) {
        const float* wp = W2 + (4 * k4) * H + 4 * q;
        float4 w0 = ld4(wp), w1 = ld4(wp + H), w2 = ld4(wp + 2 * H), w3 = ld4(wp + 3 * H);
#pragma unroll
        for (int i = 0; i < 8; ++i) {
            float4 t = *reinterpret_cast<const float4*>(&uls[(no * 8 + i) * H + 4 * k4]);
            fma4(acc2[i], t.x, w0); fma4(acc2[i], t.y, w1);
            fma4(acc2[i], t.z, w2); fma4(acc2[i], t.w, w3);
        }
    }
#pragma unroll
    for (int i = 0; i < 8; ++i) {
        int n = nbase + no * 8 + i;
        if (n < NN) st4(hout + n * H + 4 * q, acc2[i]);
    }
}

__global__ __launch_bounds__(256) void pool_kernel(const float* __restrict__ h,
    const int* __restrict__ batch, float* __restrict__ ssum,
    unsigned int* __restrict__ smaxk, float* __restrict__ cnt)
{
    const int tid = threadIdx.x, j = tid & 127, half = tid >> 7;
    const int nbase = blockIdx.x * 64;
    int cur = -1, rc = 0;
    float s = 0.f, mx = 0.f;
    for (int i = 0; i < 32; ++i) {
        int n = nbase + 2 * i + half;
        if (n >= NN) break;
        int g = batch[n];
        float v = h[(size_t)n * H + j];
        if (g != cur) {
            if (cur >= 0) {
                atomicAdd(&ssum[cur * H + j], s);
                atomicMax(&smaxk[cur * H + j], fkey(mx));
                if (j == 0) atomicAdd(&cnt[cur], (float)rc);
            }
            cur = g; s = v; mx = v; rc = 1;
        } else { s += v; mx = fmaxf(mx, v); rc++; }
    }
    if (cur >= 0) {
        atomicAdd(&ssum[cur * H + j], s);
        atomicMax(&smaxk[cur * H + j], fkey(mx));
        if (j == 0) atomicAdd(&cnt[cur], (float)rc);
    }
}

__global__ __launch_bounds__(128) void readout_kernel(const float* __restrict__ ssum,
    const unsigned int* __restrict__ smaxk, const float* __restrict__ cnt,
    const float* __restrict__ rW1, const float* __restrict__ rb1,
    const float* __restrict__ rW2, const float* __restrict__ rb2,
    const float* __restrict__ rW3, const float* __restrict__ rb3,
    float* __restrict__ out)
{
    __shared__ float p[384], h1[128], h2[64];
    const int g = blockIdx.x, j = threadIdx.x;
    float c = fmaxf(cnt[g], 1.0f);
    float sv = ssum[g * H + j];
    p[j] = sv / c;
    p[128 + j] = funkey(smaxk[g * H + j]);
    p[256 + j] = sv;
    __syncthreads();
    float a = rb1[j];
    for (int k = 0; k < 384; ++k) a = fmaf(p[k], rW1[k * H + j], a);
    h1[j] = fmaxf(a, 0.f);
    __syncthreads();
    if (j < 64) {
        float a2 = rb2[j];
        for (int k = 0; k < 128; ++k) a2 = fmaf(h1[k], rW2[k * 64 + j], a2);
        h2[j] = fmaxf(a2, 0.f);
    }
    __syncthreads();
    if (j < 64) {
        float t = h2[j] * rW3[j];
        for (int off = 32; off; off >>= 1) t += __shfl_down(t, off);
        if (j == 0) {
            float z = t + rb3[0];
            out[g] = z > 20.f ? z : log1pf(expf(z));
        }
    }
}

extern "C" void kernel_launch(void* const* d_in, const int* in_sizes, int n_in,
                              void* d_out, int out_size, void* d_ws, size_t ws_size,
                              hipStream_t stream)
{
    const float* x    = (const float*)d_in[0];
    const float* pos  = (const float*)d_in[1];
    const float* ea   = (const float*)d_in[2];
    const int*   ei   = (const int*)d_in[3];
    const int*   batch= (const int*)d_in[4];
    const float* encW = (const float*)d_in[5];
    const float* encb = (const float*)d_in[6];
    const float* eW1  = (const float*)d_in[7];
    const float* eb1  = (const float*)d_in[8];
    const float* eW2  = (const float*)d_in[9];
    const float* eb2  = (const float*)d_in[10];
    const float* nW1  = (const float*)d_in[11];
    const float* nb1  = (const float*)d_in[12];
    const float* nW2  = (const float*)d_in[13];
    const float* nb2  = (const float*)d_in[14];
    const float* rW1  = (const float*)d_in[15];
    const float* rb1  = (const float*)d_in[16];
    const float* rW2  = (const float*)d_in[17];
    const float* rb2  = (const float*)d_in[18];
    const float* rW3  = (const float*)d_in[19];
    const float* rb3  = (const float*)d_in[20];

    char* w = (char*)d_ws;
    size_t o = 0;
    auto alloc = [&](size_t bytes) -> char* {
        char* p = w + o; o += (bytes + 255) / 256 * 256; return p;
    };
    float* hA   = (float*)alloc((size_t)NN * H * 4);
    float* hB   = (float*)alloc((size_t)NN * H * 4);
    float* Pd   = (float*)alloc((size_t)NN * H * 4);
    float* Ps   = (float*)alloc((size_t)NN * H * 4);
    float* agg  = (float*)alloc((size_t)NN * H * 4);
    float* d2   = (float*)alloc((size_t)NE * 4);
    float* ssum = (float*)alloc((size_t)NG * H * 4);
    unsigned int* smaxk = (unsigned int*)alloc((size_t)NG * H * 4);
    float* cnt  = (float*)alloc((size_t)NG * 4);
    int*   deg    = (int*)alloc((size_t)NN * 4);
    int*   cursor = (int*)alloc((size_t)NN * 4);
    int*   src_s  = (int*)alloc((size_t)NE * 4);
    int*   dst_s  = (int*)alloc((size_t)NE * 4);
    float* ea_s   = (float*)alloc((size_t)NE * DEA * 4);
    float* d2_s   = (float*)alloc((size_t)NE * 4);
    ushort* w2hi  = (ushort*)alloc((size_t)NL * H * H * 2);
    ushort* w2lo  = (ushort*)alloc((size_t)NL * H * H * 2);
    (void)ws_size; (void)in_sizes; (void)n_in; (void)out_size;

    const int NB = (NN + 63) / 64;
    const int EB = (NE + 255) / 256;

    // dst-sorted edge arrays (counting sort) + per-layer W2 bf16 split/transpose
    hipMemsetAsync(deg, 0, (size_t)NN * 4, stream);
    dist2_kernel<<<EB, 256, 0, stream>>>(pos, ei, d2);
    hist_kernel<<<EB, 256, 0, stream>>>(ei, deg);
    scan_kernel<<<1, 256, 0, stream>>>(deg, cursor);
    scatter_kernel<<<EB, 256, 0, stream>>>(ei, ea, d2, cursor, src_s, dst_s, ea_s, d2_s);
    w2prep_kernel<<<NL, 256, 0, stream>>>(eW2, w2hi, w2lo);

    encoder_kernel<<<NB, 256, 0, stream>>>(x, encW, encb, hA);

    float* hcur = hA;
    float* hnext = hB;
    for (int l = 0; l < NL; ++l) {
        hipMemsetAsync(agg, 0, (size_t)NN * H * 4, stream);
        const float* W1 = eW1 + (size_t)l * 273 * H;
        proj_kernel<<<NB, 256, 0, stream>>>(hcur, W1, Pd, Ps);
        edge_mfma_kernel<<<NE / EPB, 512, 0, stream>>>(Pd, Ps, ea_s, d2_s, src_s, dst_s,
            W1, eb1 + l * H, w2hi + (size_t)l * H * H, w2lo + (size_t)l * H * H,
            eb2 + l * H, agg);
        node_kernel<<<NB, 256, 0, stream>>>(hcur, agg,
            nW1 + (size_t)l * 256 * H, nb1 + l * H, nW2 + (size_t)l * H * H, nb2 + l * H, hnext);
        float* tmp = hcur; hcur = hnext; hnext = tmp;
    }

    hipMemsetAsync(ssum, 0, (size_t)NG * H * 4, stream);
    hipMemsetAsync(smaxk, 0, (size_t)NG * H * 4, stream);
    hipMemsetAsync(cnt, 0, (size_t)NG * 4, stream);
    pool_kernel<<<NB, 256, 0, stream>>>(hcur, batch, ssum, smaxk, cnt);
    readout_kernel<<<NG, 128, 0, stream>>>(ssum, smaxk, cnt,
        rW1, rb1, rW2, rb2, rW3, rb3, (float*)d_out);
}

// Round 4
// 2791.314 us; speedup vs baseline: 3.0972x; 1.0745x over previous
//
#include <hip/hip_runtime.h>
#include <math.h>

#define NN 50000
#define NE 800000
#define NG 64
#define DIN 64
#define DEA 16
#define H 128
#define NL 4
#define EPB 128   // edges per block in edge_mfma_kernel

typedef __attribute__((ext_vector_type(8))) short short8;
typedef __attribute__((ext_vector_type(4))) float f32x4;

__device__ __forceinline__ float4 ld4(const float* p) { return *reinterpret_cast<const float4*>(p); }
__device__ __forceinline__ void st4(float* p, float4 v) { *reinterpret_cast<float4*>(p) = v; }
__device__ __forceinline__ void fma4(float4& a, float s, float4 w) {
    a.x = fmaf(s, w.x, a.x); a.y = fmaf(s, w.y, a.y);
    a.z = fmaf(s, w.z, a.z); a.w = fmaf(s, w.w, a.w);
}
__device__ __forceinline__ float4 f4add(float4 a, float4 b) {
    return make_float4(a.x + b.x, a.y + b.y, a.z + b.z, a.w + b.w);
}
__device__ __forceinline__ float4 relu4(float4 a) {
    return make_float4(fmaxf(a.x, 0.f), fmaxf(a.y, 0.f), fmaxf(a.z, 0.f), fmaxf(a.w, 0.f));
}
__device__ __forceinline__ unsigned fkey(float f) {
    unsigned b = __float_as_uint(f);
    return (b & 0x80000000u) ? ~b : (b | 0x80000000u);
}
__device__ __forceinline__ float funkey(unsigned k) {
    unsigned b = (k & 0x80000000u) ? (k ^ 0x80000000u) : ~k;
    return __uint_as_float(b);
}
__device__ __forceinline__ ushort f2bf(float f) {
    unsigned u = __float_as_uint(f);
    return (ushort)((u + 0x7fffu + ((u >> 16) & 1u)) >> 16);
}
__device__ __forceinline__ float bf2f(ushort b) {
    return __uint_as_float(((unsigned)b) << 16);
}

// h = relu(x @ encW + encb), x:[NN,64], W:[64,128]
__global__ __launch_bounds__(256) void encoder_kernel(const float* __restrict__ x,
    const float* __restrict__ W, const float* __restrict__ b, float* __restrict__ h)
{
    const int tid = threadIdx.x, q = tid & 31, no = tid >> 5;
    const int nbase = blockIdx.x * 64;
    float4 bv = ld4(b + 4 * q);
    float4 acc[8];
#pragma unroll
    for (int i = 0; i < 8; ++i) acc[i] = bv;
    for (int k4 = 0; k4 < 16; ++k4) {
        const float* wp = W + (4 * k4) * H + 4 * q;
        float4 w0 = ld4(wp), w1 = ld4(wp + H), w2 = ld4(wp + 2 * H), w3 = ld4(wp + 3 * H);
#pragma unroll
        for (int i = 0; i < 8; ++i) {
            int n = nbase + no * 8 + i; n = n < NN ? n : NN - 1;
            float4 a = ld4(x + n * DIN + 4 * k4);
            fma4(acc[i], a.x, w0); fma4(acc[i], a.y, w1);
            fma4(acc[i], a.z, w2); fma4(acc[i], a.w, w3);
        }
    }
#pragma unroll
    for (int i = 0; i < 8; ++i) {
        int n = nbase + no * 8 + i;
        if (n < NN) st4(h + n * H + 4 * q, relu4(acc[i]));
    }
}

__global__ __launch_bounds__(256) void dist2_kernel(const float* __restrict__ pos,
    const int* __restrict__ ei, float* __restrict__ d2)
{
    int e = blockIdx.x * 256 + threadIdx.x;
    if (e >= NE) return;
    int s = ei[e], d = ei[NE + e];
    float dx = pos[s * 3 + 0] - pos[d * 3 + 0];
    float dy = pos[s * 3 + 1] - pos[d * 3 + 1];
    float dz = pos[s * 3 + 2] - pos[d * 3 + 2];
    d2[e] = dx * dx + dy * dy + dz * dz;
}

// ---------- counting sort of edges by dst ----------
__global__ __launch_bounds__(256) void hist_kernel(const int* __restrict__ ei, int* __restrict__ deg)
{
    int e = blockIdx.x * 256 + threadIdx.x;
    if (e < NE) atomicAdd(&deg[ei[NE + e]], 1);
}

__global__ __launch_bounds__(256) void scan_kernel(const int* __restrict__ deg, int* __restrict__ cursor)
{
    __shared__ int tot[256];
    const int t = threadIdx.x;
    const int CH = (NN + 255) / 256;
    const int base = t * CH;
    int s = 0;
    for (int i = 0; i < CH; ++i) {
        int idx = base + i;
        if (idx < NN) s += deg[idx];
    }
    tot[t] = s;
    __syncthreads();
    for (int off = 1; off < 256; off <<= 1) {
        int v = (t >= off) ? tot[t - off] : 0;
        __syncthreads();
        tot[t] += v;
        __syncthreads();
    }
    int run = (t == 0) ? 0 : tot[t - 1];
    for (int i = 0; i < CH; ++i) {
        int idx = base + i;
        if (idx < NN) { cursor[idx] = run; run += deg[idx]; }
    }
}

__global__ __launch_bounds__(256) void scatter_kernel(const int* __restrict__ ei,
    const float* __restrict__ ea, const float* __restrict__ d2, int* __restrict__ cursor,
    int* __restrict__ src_s, int* __restrict__ dst_s,
    float* __restrict__ ea_s, float* __restrict__ d2_s)
{
    int e = blockIdx.x * 256 + threadIdx.x;
    if (e >= NE) return;
    int s = ei[e], d = ei[NE + e];
    int pos = atomicAdd(&cursor[d], 1);
    src_s[pos] = s; dst_s[pos] = d; d2_s[pos] = d2[e];
    const float4* ev = reinterpret_cast<const float4*>(ea + (size_t)e * DEA);
    float4* ov = reinterpret_cast<float4*>(ea_s + (size_t)pos * DEA);
    ov[0] = ev[0]; ov[1] = ev[1]; ov[2] = ev[2]; ov[3] = ev[3];
}

// ---------- per-layer W2 -> split bf16 (hi+lo), transposed [n][k], swizzled ----------
// dest layout (ushort units, per layer 16384): pos = half*8192 + n*64 + (kk ^ ((n&7)<<3)), kk=k&63
__global__ __launch_bounds__(256) void w2prep_kernel(const float* __restrict__ eW2,
    ushort* __restrict__ hi, ushort* __restrict__ lo)
{
    int l = blockIdx.x;
    const float* W = eW2 + (size_t)l * H * H;
    ushort* hg = hi + (size_t)l * H * H;
    ushort* lg = lo + (size_t)l * H * H;
    for (int idx = threadIdx.x; idx < H * H; idx += 256) {
        int k = idx >> 7, n = idx & 127;
        float wv = W[idx];
        ushort hb = f2bf(wv);
        float rem = wv - bf2f(hb);
        ushort lb = f2bf(rem);
        int half = k >> 6, kk = k & 63;
        int pos = (half << 13) + (n << 6) + (kk ^ ((n & 7) << 3));
        hg[pos] = hb; lg[pos] = lb;
    }
}

// Pd = h @ W1[0:128], Ps = h @ W1[128:256]
__global__ __launch_bounds__(256) void proj_kernel(const float* __restrict__ h,
    const float* __restrict__ W1, float* __restrict__ Pd, float* __restrict__ Ps)
{
    const int tid = threadIdx.x, q = tid & 31, no = tid >> 5;
    const int nbase = blockIdx.x * 64;
    float4 ad[8], as[8];
#pragma unroll
    for (int i = 0; i < 8; ++i) { ad[i] = make_float4(0, 0, 0, 0); as[i] = make_float4(0, 0, 0, 0); }
    for (int k4 = 0; k4 < 32; ++k4) {
        const float* wdp = W1 + (4 * k4) * H + 4 * q;
        const float* wsp = W1 + (128 + 4 * k4) * H + 4 * q;
        float4 wd0 = ld4(wdp), wd1 = ld4(wdp + H), wd2 = ld4(wdp + 2 * H), wd3 = ld4(wdp + 3 * H);
        float4 ws0 = ld4(wsp), ws1 = ld4(wsp + H), ws2 = ld4(wsp + 2 * H), ws3 = ld4(wsp + 3 * H);
#pragma unroll
        for (int i = 0; i < 8; ++i) {
            int n = nbase + no * 8 + i; n = n < NN ? n : NN - 1;
            float4 a = ld4(h + n * H + 4 * k4);
            fma4(ad[i], a.x, wd0); fma4(ad[i], a.y, wd1); fma4(ad[i], a.z, wd2); fma4(ad[i], a.w, wd3);
            fma4(as[i], a.x, ws0); fma4(as[i], a.y, ws1); fma4(as[i], a.z, ws2); fma4(as[i], a.w, ws3);
        }
    }
#pragma unroll
    for (int i = 0; i < 8; ++i) {
        int n = nbase + no * 8 + i;
        if (n < NN) { st4(Pd + n * H + 4 * q, ad[i]); st4(Ps + n * H + 4 * q, as[i]); }
    }
}

// dst-sorted edges, 128 edges/block, 8 waves.
// stage1 (fp32 VALU, ILP-restructured): t = relu(Pd[dst]+Ps[src]+ea@Wea+d2*wd+b1) -> bf16 swizzled LDS
// stage2 (MFMA bf16): m = relu(t @ (W2hi+W2lo) + b2), segmented atomic flush to agg
__global__ __launch_bounds__(512, 4) void edge_mfma_kernel(
    const float* __restrict__ Pd, const float* __restrict__ Ps,
    const float* __restrict__ ea_s, const float* __restrict__ d2_s,
    const int* __restrict__ src_s, const int* __restrict__ dst_s,
    const float* __restrict__ W1, const float* __restrict__ b1,
    const ushort* __restrict__ w2hiL, const ushort* __restrict__ w2loL,
    const float* __restrict__ b2, float* __restrict__ agg)
{
    __shared__ __align__(16) ushort tls[EPB * H];   // 32KB: t bf16, swizzled rows
    __shared__ __align__(16) ushort whi[H * 64];    // 16KB: W2hi^T k-half, swizzled
    __shared__ __align__(16) ushort wlo[H * 64];    // 16KB

    const int tid = threadIdx.x, q = tid & 31, eo = tid >> 5;   // eo in [0,16)
    const int ebase = blockIdx.x * EPB;

    // prefetch W k-half 0 (hi+lo) into regs; pre-swizzled in global, linear copy
    const int4* ghi = (const int4*)w2hiL;
    const int4* glo = (const int4*)w2loL;
    int4 rh0[2], rl0[2];
    rh0[0] = ghi[tid]; rh0[1] = ghi[tid + 512];
    rl0[0] = glo[tid]; rl0[1] = glo[tid + 512];

    // ---- stage 1: edge MLP layer-1 (fp32), ILP-restructured ----
    const float* Wea = W1 + 256 * H;
    const float* wdv = W1 + 272 * H;
    float4 b1v = ld4(b1 + 4 * q);
    float4 wdq = ld4(wdv + 4 * q);

    int srcs[8], dsts8[8];
    float d2v[8];
#pragma unroll
    for (int i = 0; i < 8; ++i) {
        int j = ebase + eo * 8 + i;
        srcs[i] = src_s[j]; dsts8[i] = dst_s[j]; d2v[i] = d2_s[j];
    }
    float4 acc1[8];
#pragma unroll
    for (int i = 0; i < 8; ++i) {
        float4 a = f4add(ld4(Pd + (size_t)dsts8[i] * H + 4 * q),
                         ld4(Ps + (size_t)srcs[i] * H + 4 * q));
        a = f4add(a, b1v);
        fma4(a, d2v[i], wdq);
        acc1[i] = a;
    }
#pragma unroll
    for (int k4 = 0; k4 < 4; ++k4) {
        float4 w0 = ld4(Wea + (4 * k4 + 0) * H + 4 * q);
        float4 w1 = ld4(Wea + (4 * k4 + 1) * H + 4 * q);
        float4 w2 = ld4(Wea + (4 * k4 + 2) * H + 4 * q);
        float4 w3 = ld4(Wea + (4 * k4 + 3) * H + 4 * q);
#pragma unroll
        for (int i = 0; i < 8; ++i) {
            int j = ebase + eo * 8 + i;
            float4 av = ld4(ea_s + (size_t)j * DEA + 4 * k4);
            fma4(acc1[i], av.x, w0); fma4(acc1[i], av.y, w1);
            fma4(acc1[i], av.z, w2); fma4(acc1[i], av.w, w3);
        }
    }
#pragma unroll
    for (int i = 0; i < 8; ++i) {
        int el = eo * 8 + i;
        ushort4 tv;
        tv.x = f2bf(fmaxf(acc1[i].x, 0.f)); tv.y = f2bf(fmaxf(acc1[i].y, 0.f));
        tv.z = f2bf(fmaxf(acc1[i].z, 0.f)); tv.w = f2bf(fmaxf(acc1[i].w, 0.f));
        int tidx = el * H + ((4 * q) ^ ((el & 7) << 3));
        *reinterpret_cast<ushort4*>(&tls[tidx]) = tv;
    }

    // write W half0 to LDS, prefetch half1
    ((int4*)whi)[tid] = rh0[0]; ((int4*)whi)[tid + 512] = rh0[1];
    ((int4*)wlo)[tid] = rl0[0]; ((int4*)wlo)[tid + 512] = rl0[1];
    int4 rh1[2], rl1[2];
    rh1[0] = ghi[1024 + tid]; rh1[1] = ghi[1024 + tid + 512];
    rl1[0] = glo[1024 + tid]; rl1[1] = glo[1024 + tid + 512];
    __syncthreads();

    // ---- stage 2: MFMA t @ W2 ----
    const int lane = tid & 63, wv = tid >> 6;   // 8 waves x 16 rows
    const int col = lane & 15, g = lane >> 4;
    f32x4 acc[8];
#pragma unroll
    for (int nt = 0; nt < 8; ++nt) {
        float bb = b2[nt * 16 + col];
        acc[nt] = (f32x4){bb, bb, bb, bb};
    }
    const int arow = wv * 16 + col;
    const int aswz = (arow & 7) << 3;

#define KSTEP(k0, kk0)                                                            \
    {                                                                             \
        short8 af = *(const short8*)&tls[arow * H + (((k0) + 8 * g) ^ aswz)];     \
        _Pragma("unroll")                                                         \
        for (int nt = 0; nt < 8; ++nt) {                                          \
            int brow = nt * 16 + col;                                             \
            int bidx = brow * 64 + (((kk0) + 8 * g) ^ ((brow & 7) << 3));         \
            short8 bh = *(const short8*)&whi[bidx];                               \
            short8 bl = *(const short8*)&wlo[bidx];                               \
            acc[nt] = __builtin_amdgcn_mfma_f32_16x16x32_bf16(af, bh, acc[nt], 0, 0, 0); \
            acc[nt] = __builtin_amdgcn_mfma_f32_16x16x32_bf16(af, bl, acc[nt], 0, 0, 0); \
        }                                                                         \
    }

    __builtin_amdgcn_s_setprio(1);
    KSTEP(0, 0)
    KSTEP(32, 32)
    __builtin_amdgcn_s_setprio(0);
    __syncthreads();
    ((int4*)whi)[tid] = rh1[0]; ((int4*)whi)[tid + 512] = rh1[1];
    ((int4*)wlo)[tid] = rl1[0]; ((int4*)wlo)[tid + 512] = rl1[1];
    __syncthreads();
    __builtin_amdgcn_s_setprio(1);
    KSTEP(64, 0)
    KSTEP(96, 32)
    __builtin_amdgcn_s_setprio(0);
#undef KSTEP

    // ---- flush: C frag rows = edges (row=(lane>>4)*4+reg), cols = nt*16 + (lane&15) ----
    const int growbase = ebase + wv * 16 + g * 4;
    int dr[4];
#pragma unroll
    for (int r = 0; r < 4; ++r) dr[r] = dst_s[growbase + r];
    float vrun[8];
    int dcur = dr[0];
#pragma unroll
    for (int nt = 0; nt < 8; ++nt) vrun[nt] = fmaxf(acc[nt][0], 0.f);
#pragma unroll
    for (int r = 1; r < 4; ++r) {
        if (dr[r] != dcur) {
#pragma unroll
            for (int nt = 0; nt < 8; ++nt) {
                atomicAdd(&agg[(size_t)dcur * H + nt * 16 + col], vrun[nt]);
                vrun[nt] = fmaxf(acc[nt][r], 0.f);
            }
            dcur = dr[r];
        } else {
#pragma unroll
            for (int nt = 0; nt < 8; ++nt) vrun[nt] += fmaxf(acc[nt][r], 0.f);
        }
    }
#pragma unroll
    for (int nt = 0; nt < 8; ++nt)
        atomicAdd(&agg[(size_t)dcur * H + nt * 16 + col], vrun[nt]);
}

// h' = relu([h,agg] @ nW1 + nb1) @ nW2 + nb2   (no final relu)
__global__ __launch_bounds__(256) void node_kernel(
    const float* __restrict__ h, const float* __restrict__ agg,
    const float* __restrict__ W1, const float* __restrict__ b1,
    const float* __restrict__ W2, const float* __restrict__ b2,
    float* __restrict__ hout)
{
    __shared__ float uls[64 * H];
    const int tid = threadIdx.x, q = tid & 31, no = tid >> 5;
    const int nbase = blockIdx.x * 64;
    float4 acc[8];
    float4 b1v = ld4(b1 + 4 * q);
#pragma unroll
    for (int i = 0; i < 8; ++i) acc[i] = b1v;
    for (int k4 = 0; k4 < 32; ++k4) {
        const float* wp = W1 + (4 * k4) * H + 4 * q;
        float4 w0 = ld4(wp), w1 = ld4(wp + H), w2 = ld4(wp + 2 * H), w3 = ld4(wp + 3 * H);
#pragma unroll
        for (int i = 0; i < 8; ++i) {
            int n = nbase + no * 8 + i; n = n < NN ? n : NN - 1;
            float4 a = ld4(h + n * H + 4 * k4);
            fma4(acc[i], a.x, w0); fma4(acc[i], a.y, w1);
            fma4(acc[i], a.z, w2); fma4(acc[i], a.w, w3);
        }
    }
    for (int k4 = 0; k4 < 32; ++k4) {
        const float* wp = W1 + (128 + 4 * k4) * H + 4 * q;
        float4 w0 = ld4(wp), w1 = ld4(wp + H), w2 = ld4(wp + 2 * H), w3 = ld4(wp + 3 * H);
#pragma unroll
        for (int i = 0; i < 8; ++i) {
            int n = nbase + no * 8 + i; n = n < NN ? n : NN - 1;
            float4 a = ld4(agg + n * H + 4 * k4);
            fma4(acc[i], a.x, w0); fma4(acc[i], a.y, w1);
            fma4(acc[i], a.z, w2); fma4(acc[i], a.w, w3);
        }
    }
#pragma unroll
    for (int i = 0; i < 8; ++i) st4(&uls[(no * 8 + i) * H + 4 * q], relu4(acc[i]));
    __syncthreads();
    float4 acc2[8];
    float4 b2v = ld4(b2 + 4 * q);
#pragma unroll
    for (int i = 0; i < 8; ++i) acc2[i] = b2v;
    for (int k4 = 0; k4 < 32; ++k4) {
        const float* wp = W2 + (4 * k4) * H + 4 * q;
        float4 w0 = ld4(wp), w1 = ld4(wp + H), w2 = ld4(wp + 2 * H), w3 = ld4(wp + 3 * H);
#pragma unroll
        for (int i = 0; i < 8; ++i) {
            float4 t = *reinterpret_cast<const float4*>(&uls[(no * 8 + i) * H + 4 * k4]);
            fma4(acc2[i], t.x, w0); fma4(acc2[i], t.y, w1);
            fma4(acc2[i], t.z, w2); fma4(acc2[i], t.w, w3);
        }
    }
#pragma unroll
    for (int i = 0; i < 8; ++i) {
        int n = nbase + no * 8 + i;
        if (n < NN) st4(hout + n * H + 4 * q, acc2[i]);
    }
}

__global__ __launch_bounds__(256) void pool_kernel(const float* __restrict__ h,
    const int* __restrict__ batch, float* __restrict__ ssum,
    unsigned int* __restrict__ smaxk, float* __restrict__ cnt)
{
    const int tid = threadIdx.x, j = tid & 127, half = tid >> 7;
    const int nbase = blockIdx.x * 64;
    int cur = -1, rc = 0;
    float s = 0.f, mx = 0.f;
    for (int i = 0; i < 32; ++i) {
        int n = nbase + 2 * i + half;
        if (n >= NN) break;
        int g = batch[n];
        float v = h[(size_t)n * H + j];
        if (g != cur) {
            if (cur >= 0) {
                atomicAdd(&ssum[cur * H + j], s);
                atomicMax(&smaxk[cur * H + j], fkey(mx));
                if (j == 0) atomicAdd(&cnt[cur], (float)rc);
            }
            cur = g; s = v; mx = v; rc = 1;
        } else { s += v; mx = fmaxf(mx, v); rc++; }
    }
    if (cur >= 0) {
        atomicAdd(&ssum[cur * H + j], s);
        atomicMax(&smaxk[cur * H + j], fkey(mx));
        if (j == 0) atomicAdd(&cnt[cur], (float)rc);
    }
}

__global__ __launch_bounds__(128) void readout_kernel(const float* __restrict__ ssum,
    const unsigned int* __restrict__ smaxk, const float* __restrict__ cnt,
    const float* __restrict__ rW1, const float* __restrict__ rb1,
    const float* __restrict__ rW2, const float* __restrict__ rb2,
    const float* __restrict__ rW3, const float* __restrict__ rb3,
    float* __restrict__ out)
{
    __shared__ float p[384], h1[128], h2[64];
    const int g = blockIdx.x, j = threadIdx.x;
    float c = fmaxf(cnt[g], 1.0f);
    float sv = ssum[g * H + j];
    p[j] = sv / c;
    p[128 + j] = funkey(smaxk[g * H + j]);
    p[256 + j] = sv;
    __syncthreads();
    float a = rb1[j];
    for (int k = 0; k < 384; ++k) a = fmaf(p[k], rW1[k * H + j], a);
    h1[j] = fmaxf(a, 0.f);
    __syncthreads();
    if (j < 64) {
        float a2 = rb2[j];
        for (int k = 0; k < 128; ++k) a2 = fmaf(h1[k], rW2[k * 64 + j], a2);
        h2[j] = fmaxf(a2, 0.f);
    }
    __syncthreads();
    if (j < 64) {
        float t = h2[j] * rW3[j];
        for (int off = 32; off; off >>= 1) t += __shfl_down(t, off);
        if (j == 0) {
            float z = t + rb3[0];
            out[g] = z > 20.f ? z : log1pf(expf(z));
        }
    }
}

extern "C" void kernel_launch(void* const* d_in, const int* in_sizes, int n_in,
                              void* d_out, int out_size, void* d_ws, size_t ws_size,
                              hipStream_t stream)
{
    const float* x    = (const float*)d_in[0];
    const float* pos  = (const float*)d_in[1];
    const float* ea   = (const float*)d_in[2];
    const int*   ei   = (const int*)d_in[3];
    const int*   batch= (const int*)d_in[4];
    const float* encW = (const float*)d_in[5];
    const float* encb = (const float*)d_in[6];
    const float* eW1  = (const float*)d_in[7];
    const float* eb1  = (const float*)d_in[8];
    const float* eW2  = (const float*)d_in[9];
    const float* eb2  = (const float*)d_in[10];
    const float* nW1  = (const float*)d_in[11];
    const float* nb1  = (const float*)d_in[12];
    const float* nW2  = (const float*)d_in[13];
    const float* nb2  = (const float*)d_in[14];
    const float* rW1  = (const float*)d_in[15];
    const float* rb1  = (const float*)d_in[16];
    const float* rW2  = (const float*)d_in[17];
    const float* rb2  = (const float*)d_in[18];
    const float* rW3  = (const float*)d_in[19];
    const float* rb3  = (const float*)d_in[20];

    char* w = (char*)d_ws;
    size_t o = 0;
    auto alloc = [&](size_t bytes) -> char* {
        char* p = w + o; o += (bytes + 255) / 256 * 256; return p;
    };
    float* hA   = (float*)alloc((size_t)NN * H * 4);
    float* hB   = (float*)alloc((size_t)NN * H * 4);
    float* Pd   = (float*)alloc((size_t)NN * H * 4);
    float* Ps   = (float*)alloc((size_t)NN * H * 4);
    float* agg  = (float*)alloc((size_t)NN * H * 4);
    float* d2   = (float*)alloc((size_t)NE * 4);
    float* ssum = (float*)alloc((size_t)NG * H * 4);
    unsigned int* smaxk = (unsigned int*)alloc((size_t)NG * H * 4);
    float* cnt  = (float*)alloc((size_t)NG * 4);
    int*   deg    = (int*)alloc((size_t)NN * 4);
    int*   cursor = (int*)alloc((size_t)NN * 4);
    int*   src_s  = (int*)alloc((size_t)NE * 4);
    int*   dst_s  = (int*)alloc((size_t)NE * 4);
    float* ea_s   = (float*)alloc((size_t)NE * DEA * 4);
    float* d2_s   = (float*)alloc((size_t)NE * 4);
    ushort* w2hi  = (ushort*)alloc((size_t)NL * H * H * 2);
    ushort* w2lo  = (ushort*)alloc((size_t)NL * H * H * 2);
    (void)ws_size; (void)in_sizes; (void)n_in; (void)out_size;

    const int NB = (NN + 63) / 64;
    const int EB = (NE + 255) / 256;

    // dst-sorted edge arrays (counting sort) + per-layer W2 bf16 split/transpose
    hipMemsetAsync(deg, 0, (size_t)NN * 4, stream);
    dist2_kernel<<<EB, 256, 0, stream>>>(pos, ei, d2);
    hist_kernel<<<EB, 256, 0, stream>>>(ei, deg);
    scan_kernel<<<1, 256, 0, stream>>>(deg, cursor);
    scatter_kernel<<<EB, 256, 0, stream>>>(ei, ea, d2, cursor, src_s, dst_s, ea_s, d2_s);
    w2prep_kernel<<<NL, 256, 0, stream>>>(eW2, w2hi, w2lo);

    encoder_kernel<<<NB, 256, 0, stream>>>(x, encW, encb, hA);

    float* hcur = hA;
    float* hnext = hB;
    for (int l = 0; l < NL; ++l) {
        hipMemsetAsync(agg, 0, (size_t)NN * H * 4, stream);
        const float* W1 = eW1 + (size_t)l * 273 * H;
        proj_kernel<<<NB, 256, 0, stream>>>(hcur, W1, Pd, Ps);
        edge_mfma_kernel<<<NE / EPB, 512, 0, stream>>>(Pd, Ps, ea_s, d2_s, src_s, dst_s,
            W1, eb1 + l * H, w2hi + (size_t)l * H * H, w2lo + (size_t)l * H * H,
            eb2 + l * H, agg);
        node_kernel<<<NB, 256, 0, stream>>>(hcur, agg,
            nW1 + (size_t)l * 256 * H, nb1 + l * H, nW2 + (size_t)l * H * H, nb2 + l * H, hnext);
        float* tmp = hcur; hcur = hnext; hnext = tmp;
    }

    hipMemsetAsync(ssum, 0, (size_t)NG * H * 4, stream);
    hipMemsetAsync(smaxk, 0, (size_t)NG * H * 4, stream);
    hipMemsetAsync(cnt, 0, (size_t)NG * 4, stream);
    pool_kernel<<<NB, 256, 0, stream>>>(hcur, batch, ssum, smaxk, cnt);
    readout_kernel<<<NG, 128, 0, stream>>>(ssum, smaxk, cnt,
        rW1, rb1, rW2, rb2, rW3, rb3, (float*)d_out);
}

// Round 5
// 2214.505 us; speedup vs baseline: 3.9040x; 1.2605x over previous
//
#include <hip/hip_runtime.h>
#include <math.h>

#define NN 50000
#define NE 800000
#define NG 64
#define DIN 64
#define DEA 16
#define H 128
#define NL 4
#define EPB 128   // edges per block in edge_mfma_kernel

typedef __attribute__((ext_vector_type(8))) short short8;
typedef __attribute__((ext_vector_type(4))) float f32x4;

__device__ __forceinline__ float4 ld4(const float* p) { return *reinterpret_cast<const float4*>(p); }
__device__ __forceinline__ void st4(float* p, float4 v) { *reinterpret_cast<float4*>(p) = v; }
__device__ __forceinline__ void fma4(float4& a, float s, float4 w) {
    a.x = fmaf(s, w.x, a.x); a.y = fmaf(s, w.y, a.y);
    a.z = fmaf(s, w.z, a.z); a.w = fmaf(s, w.w, a.w);
}
__device__ __forceinline__ float4 f4add(float4 a, float4 b) {
    return make_float4(a.x + b.x, a.y + b.y, a.z + b.z, a.w + b.w);
}
__device__ __forceinline__ float4 relu4(float4 a) {
    return make_float4(fmaxf(a.x, 0.f), fmaxf(a.y, 0.f), fmaxf(a.z, 0.f), fmaxf(a.w, 0.f));
}
__device__ __forceinline__ unsigned fkey(float f) {
    unsigned b = __float_as_uint(f);
    return (b & 0x80000000u) ? ~b : (b | 0x80000000u);
}
__device__ __forceinline__ float funkey(unsigned k) {
    unsigned b = (k & 0x80000000u) ? (k ^ 0x80000000u) : ~k;
    return __uint_as_float(b);
}
__device__ __forceinline__ ushort f2bf(float f) {
    unsigned u = __float_as_uint(f);
    return (ushort)((u + 0x7fffu + ((u >> 16) & 1u)) >> 16);
}
__device__ __forceinline__ float bf2f(ushort b) {
    return __uint_as_float(((unsigned)b) << 16);
}

// h = relu(x @ encW + encb), x:[NN,64], W:[64,128]
__global__ __launch_bounds__(256) void encoder_kernel(const float* __restrict__ x,
    const float* __restrict__ W, const float* __restrict__ b, float* __restrict__ h)
{
    const int tid = threadIdx.x, q = tid & 31, no = tid >> 5;
    const int nbase = blockIdx.x * 64;
    float4 bv = ld4(b + 4 * q);
    float4 acc[8];
#pragma unroll
    for (int i = 0; i < 8; ++i) acc[i] = bv;
    for (int k4 = 0; k4 < 16; ++k4) {
        const float* wp = W + (4 * k4) * H + 4 * q;
        float4 w0 = ld4(wp), w1 = ld4(wp + H), w2 = ld4(wp + 2 * H), w3 = ld4(wp + 3 * H);
#pragma unroll
        for (int i = 0; i < 8; ++i) {
            int n = nbase + no * 8 + i; n = n < NN ? n : NN - 1;
            float4 a = ld4(x + n * DIN + 4 * k4);
            fma4(acc[i], a.x, w0); fma4(acc[i], a.y, w1);
            fma4(acc[i], a.z, w2); fma4(acc[i], a.w, w3);
        }
    }
#pragma unroll
    for (int i = 0; i < 8; ++i) {
        int n = nbase + no * 8 + i;
        if (n < NN) st4(h + n * H + 4 * q, relu4(acc[i]));
    }
}

__global__ __launch_bounds__(256) void dist2_kernel(const float* __restrict__ pos,
    const int* __restrict__ ei, float* __restrict__ d2)
{
    int e = blockIdx.x * 256 + threadIdx.x;
    if (e >= NE) return;
    int s = ei[e], d = ei[NE + e];
    float dx = pos[s * 3 + 0] - pos[d * 3 + 0];
    float dy = pos[s * 3 + 1] - pos[d * 3 + 1];
    float dz = pos[s * 3 + 2] - pos[d * 3 + 2];
    d2[e] = dx * dx + dy * dy + dz * dz;
}

// ---------- counting sort of edges by dst ----------
__global__ __launch_bounds__(256) void hist_kernel(const int* __restrict__ ei, int* __restrict__ deg)
{
    int e = blockIdx.x * 256 + threadIdx.x;
    if (e < NE) atomicAdd(&deg[ei[NE + e]], 1);
}

__global__ __launch_bounds__(256) void scan_kernel(const int* __restrict__ deg, int* __restrict__ cursor)
{
    __shared__ int tot[256];
    const int t = threadIdx.x;
    const int CH = (NN + 255) / 256;
    const int base = t * CH;
    int s = 0;
    for (int i = 0; i < CH; ++i) {
        int idx = base + i;
        if (idx < NN) s += deg[idx];
    }
    tot[t] = s;
    __syncthreads();
    for (int off = 1; off < 256; off <<= 1) {
        int v = (t >= off) ? tot[t - off] : 0;
        __syncthreads();
        tot[t] += v;
        __syncthreads();
    }
    int run = (t == 0) ? 0 : tot[t - 1];
    for (int i = 0; i < CH; ++i) {
        int idx = base + i;
        if (idx < NN) { cursor[idx] = run; run += deg[idx]; }
    }
}

__global__ __launch_bounds__(256) void scatter_kernel(const int* __restrict__ ei,
    const float* __restrict__ ea, const float* __restrict__ d2, int* __restrict__ cursor,
    int* __restrict__ src_s, int* __restrict__ dst_s,
    float* __restrict__ ea_s, float* __restrict__ d2_s)
{
    int e = blockIdx.x * 256 + threadIdx.x;
    if (e >= NE) return;
    int s = ei[e], d = ei[NE + e];
    int pos = atomicAdd(&cursor[d], 1);
    src_s[pos] = s; dst_s[pos] = d; d2_s[pos] = d2[e];
    const float4* ev = reinterpret_cast<const float4*>(ea + (size_t)e * DEA);
    float4* ov = reinterpret_cast<float4*>(ea_s + (size_t)pos * DEA);
    ov[0] = ev[0]; ov[1] = ev[1]; ov[2] = ev[2]; ov[3] = ev[3];
}

// ---------- generic W [K x 128] -> split bf16 (hi+lo), transposed [n][k], k-panel-64 swizzled ----------
// per panel (8192 ushorts): pos = panel*8192 + n*64 + (kk ^ ((n&7)<<3))
__global__ __launch_bounds__(256) void wprep_kernel(const float* __restrict__ W,
    ushort* __restrict__ hi, ushort* __restrict__ lo,
    int K, int in_lstride, int out_lstride)
{
    int l = blockIdx.y;
    const float* Wb = W + (size_t)l * in_lstride;
    ushort* hg = hi + (size_t)l * out_lstride;
    ushort* lg = lo + (size_t)l * out_lstride;
    int total = K * 128;
    for (int idx = blockIdx.x * 256 + threadIdx.x; idx < total; idx += gridDim.x * 256) {
        int k = idx >> 7, n = idx & 127;
        float wv = Wb[idx];
        ushort hb = f2bf(wv);
        float rem = wv - bf2f(hb);
        ushort lb = f2bf(rem);
        int panel = k >> 6, kk = k & 63;
        int pos = panel * 8192 + (n << 6) + (kk ^ ((n & 7) << 3));
        hg[pos] = hb; lg[pos] = lb;
    }
}

// ---------- proj: Pd = h @ W1d, Ps = h @ W1s  (MFMA, split-bf16 weights) ----------
__global__ __launch_bounds__(512, 4) void proj_mfma_kernel(const float* __restrict__ h,
    const ushort* __restrict__ wdh, const ushort* __restrict__ wdl,
    const ushort* __restrict__ wsh, const ushort* __restrict__ wsl,
    float* __restrict__ Pd, float* __restrict__ Ps)
{
    __shared__ __align__(16) ushort Afull[128 * 128];  // 32KB
    __shared__ __align__(16) ushort Wh[128 * 64];      // 16KB
    __shared__ __align__(16) ushort Wl[128 * 64];      // 16KB
    const int tid = threadIdx.x;
    const int nbase = blockIdx.x * 128;

    // stage A = h rows, bf16, swizzled
    {
        int r = tid >> 2, kq = (tid & 3) * 32;
        int n = nbase + r; n = n < NN ? n : NN - 1;
        const float* src = h + (size_t)n * H + kq;
        int swz = (r & 7) << 3;
#pragma unroll
        for (int j = 0; j < 4; ++j) {
            float4 a = ld4(src + 8 * j * 1 + 0 + 0);
            float4 b = ld4(src + 8 * j + 4);
            union { ushort u[8]; int4 v; } pk;
            pk.u[0] = f2bf(a.x); pk.u[1] = f2bf(a.y); pk.u[2] = f2bf(a.z); pk.u[3] = f2bf(a.w);
            pk.u[4] = f2bf(b.x); pk.u[5] = f2bf(b.y); pk.u[6] = f2bf(b.z); pk.u[7] = f2bf(b.w);
            *reinterpret_cast<int4*>(&Afull[r * 128 + ((kq + 8 * j) ^ swz)]) = pk.v;
        }
    }

    const int lane = tid & 63, wvx = tid >> 6, colL = lane & 15, g = lane >> 4;
    const int arow = wvx * 16 + colL, aswz = (arow & 7) << 3;
    f32x4 accd[8], accs[8];
#pragma unroll
    for (int nt = 0; nt < 8; ++nt) { accd[nt] = (f32x4){0, 0, 0, 0}; accs[nt] = (f32x4){0, 0, 0, 0}; }

#define PROJ_ROUND(HSRC, LSRC, KOFF, ACC)                                               \
    {                                                                                   \
        ((int4*)Wh)[tid] = ((const int4*)(HSRC))[tid];                                  \
        ((int4*)Wh)[tid + 512] = ((const int4*)(HSRC))[tid + 512];                      \
        ((int4*)Wl)[tid] = ((const int4*)(LSRC))[tid];                                  \
        ((int4*)Wl)[tid + 512] = ((const int4*)(LSRC))[tid + 512];                      \
        __syncthreads();                                                                \
        _Pragma("unroll")                                                               \
        for (int ks = 0; ks < 2; ++ks) {                                                \
            int kk0 = ks * 32;                                                          \
            short8 af = *(const short8*)&Afull[arow * 128 + (((KOFF) + kk0 + 8 * g) ^ aswz)]; \
            _Pragma("unroll")                                                           \
            for (int nt = 0; nt < 8; ++nt) {                                            \
                int brow = nt * 16 + colL;                                              \
                int bidx = brow * 64 + ((kk0 + 8 * g) ^ ((brow & 7) << 3));             \
                short8 bh = *(const short8*)&Wh[bidx];                                  \
                short8 bl = *(const short8*)&Wl[bidx];                                  \
                ACC[nt] = __builtin_amdgcn_mfma_f32_16x16x32_bf16(af, bh, ACC[nt], 0, 0, 0); \
                ACC[nt] = __builtin_amdgcn_mfma_f32_16x16x32_bf16(af, bl, ACC[nt], 0, 0, 0); \
            }                                                                           \
        }                                                                               \
        __syncthreads();                                                                \
    }

    PROJ_ROUND(wdh, wdl, 0, accd)
    PROJ_ROUND(wdh + 8192, wdl + 8192, 64, accd)
    PROJ_ROUND(wsh, wsl, 0, accs)
    PROJ_ROUND(wsh + 8192, wsl + 8192, 64, accs)
#undef PROJ_ROUND

    const int rowb = wvx * 16 + g * 4;
#pragma unroll
    for (int r = 0; r < 4; ++r) {
        int n = nbase + rowb + r;
        if (n < NN) {
#pragma unroll
            for (int nt = 0; nt < 8; ++nt) {
                Pd[(size_t)n * H + nt * 16 + colL] = accd[nt][r];
                Ps[(size_t)n * H + nt * 16 + colL] = accs[nt][r];
            }
        }
    }
}

// ---------- node: h' = relu([h,agg]@nW1+b1)@nW2+b2  (MFMA, split-bf16 weights) ----------
__global__ __launch_bounds__(512, 4) void node_mfma_kernel(
    const float* __restrict__ h, const float* __restrict__ agg,
    const ushort* __restrict__ w1h, const ushort* __restrict__ w1l,
    const ushort* __restrict__ w2h, const ushort* __restrict__ w2l,
    const float* __restrict__ b1, const float* __restrict__ b2,
    float* __restrict__ hout)
{
    __shared__ __align__(16) ushort Abuf[128 * 64];    // 16KB
    __shared__ __align__(16) ushort ubuf[128 * 128];   // 32KB
    __shared__ __align__(16) ushort Wh[128 * 64];      // 16KB
    __shared__ __align__(16) ushort Wl[128 * 64];      // 16KB
    const int tid = threadIdx.x;
    const int nbase = blockIdx.x * 128;
    const int lane = tid & 63, wvx = tid >> 6, colL = lane & 15, g = lane >> 4;
    const int arow = wvx * 16 + colL, aswz = (arow & 7) << 3;

    f32x4 acc[8];
#pragma unroll
    for (int nt = 0; nt < 8; ++nt) {
        float bb = b1[nt * 16 + colL];
        acc[nt] = (f32x4){bb, bb, bb, bb};
    }

    const int sr = tid >> 2, skq = (tid & 3) * 16;
    const int sswz = (sr & 7) << 3;
    int sn = nbase + sr; sn = sn < NN ? sn : NN - 1;

#pragma unroll
    for (int kp = 0; kp < 4; ++kp) {
        // stage A panel (h cols for kp<2, agg cols for kp>=2)
        const float* srcb = (kp < 2 ? h : agg);
        const float* src = srcb + (size_t)sn * H + (kp & 1) * 64 + skq;
#pragma unroll
        for (int j = 0; j < 2; ++j) {
            float4 a = ld4(src + 8 * j);
            float4 b = ld4(src + 8 * j + 4);
            union { ushort u[8]; int4 v; } pk;
            pk.u[0] = f2bf(a.x); pk.u[1] = f2bf(a.y); pk.u[2] = f2bf(a.z); pk.u[3] = f2bf(a.w);
            pk.u[4] = f2bf(b.x); pk.u[5] = f2bf(b.y); pk.u[6] = f2bf(b.z); pk.u[7] = f2bf(b.w);
            *reinterpret_cast<int4*>(&Abuf[sr * 64 + ((skq + 8 * j) ^ sswz)]) = pk.v;
        }
        // stage W1 panel
        ((int4*)Wh)[tid] = ((const int4*)(w1h + kp * 8192))[tid];
        ((int4*)Wh)[tid + 512] = ((const int4*)(w1h + kp * 8192))[tid + 512];
        ((int4*)Wl)[tid] = ((const int4*)(w1l + kp * 8192))[tid];
        ((int4*)Wl)[tid + 512] = ((const int4*)(w1l + kp * 8192))[tid + 512];
        __syncthreads();
#pragma unroll
        for (int ks = 0; ks < 2; ++ks) {
            int kk0 = ks * 32;
            short8 af = *(const short8*)&Abuf[arow * 64 + ((kk0 + 8 * g) ^ aswz)];
#pragma unroll
            for (int nt = 0; nt < 8; ++nt) {
                int brow = nt * 16 + colL;
                int bidx = brow * 64 + ((kk0 + 8 * g) ^ ((brow & 7) << 3));
                short8 bh = *(const short8*)&Wh[bidx];
                short8 bl = *(const short8*)&Wl[bidx];
                acc[nt] = __builtin_amdgcn_mfma_f32_16x16x32_bf16(af, bh, acc[nt], 0, 0, 0);
                acc[nt] = __builtin_amdgcn_mfma_f32_16x16x32_bf16(af, bl, acc[nt], 0, 0, 0);
            }
        }
        __syncthreads();
    }

    // u = relu(acc) -> bf16 swizzled ubuf (C-layout rows)
    const int rowb = wvx * 16 + g * 4;
#pragma unroll
    for (int r = 0; r < 4; ++r) {
        int row = rowb + r;
        int rs = (row & 7) << 3;
#pragma unroll
        for (int nt = 0; nt < 8; ++nt) {
            ubuf[row * 128 + ((nt * 16 + colL) ^ rs)] = f2bf(fmaxf(acc[nt][r], 0.f));
        }
    }
    __syncthreads();

    f32x4 acc2[8];
#pragma unroll
    for (int nt = 0; nt < 8; ++nt) {
        float bb = b2[nt * 16 + colL];
        acc2[nt] = (f32x4){bb, bb, bb, bb};
    }
#pragma unroll
    for (int kp2 = 0; kp2 < 2; ++kp2) {
        ((int4*)Wh)[tid] = ((const int4*)(w2h + kp2 * 8192))[tid];
        ((int4*)Wh)[tid + 512] = ((const int4*)(w2h + kp2 * 8192))[tid + 512];
        ((int4*)Wl)[tid] = ((const int4*)(w2l + kp2 * 8192))[tid];
        ((int4*)Wl)[tid + 512] = ((const int4*)(w2l + kp2 * 8192))[tid + 512];
        __syncthreads();
#pragma unroll
        for (int ks = 0; ks < 2; ++ks) {
            int kk0 = ks * 32;
            short8 af = *(const short8*)&ubuf[arow * 128 + ((kp2 * 64 + kk0 + 8 * g) ^ aswz)];
#pragma unroll
            for (int nt = 0; nt < 8; ++nt) {
                int brow = nt * 16 + colL;
                int bidx = brow * 64 + ((kk0 + 8 * g) ^ ((brow & 7) << 3));
                short8 bh = *(const short8*)&Wh[bidx];
                short8 bl = *(const short8*)&Wl[bidx];
                acc2[nt] = __builtin_amdgcn_mfma_f32_16x16x32_bf16(af, bh, acc2[nt], 0, 0, 0);
                acc2[nt] = __builtin_amdgcn_mfma_f32_16x16x32_bf16(af, bl, acc2[nt], 0, 0, 0);
            }
        }
        __syncthreads();
    }

#pragma unroll
    for (int r = 0; r < 4; ++r) {
        int n = nbase + rowb + r;
        if (n < NN) {
#pragma unroll
            for (int nt = 0; nt < 8; ++nt)
                hout[(size_t)n * H + nt * 16 + colL] = acc2[nt][r];
        }
    }
}

// dst-sorted edges, 128 edges/block, 8 waves (unchanged from R4)
__global__ __launch_bounds__(512, 4) void edge_mfma_kernel(
    const float* __restrict__ Pd, const float* __restrict__ Ps,
    const float* __restrict__ ea_s, const float* __restrict__ d2_s,
    const int* __restrict__ src_s, const int* __restrict__ dst_s,
    const float* __restrict__ W1, const float* __restrict__ b1,
    const ushort* __restrict__ w2hiL, const ushort* __restrict__ w2loL,
    const float* __restrict__ b2, float* __restrict__ agg)
{
    __shared__ __align__(16) ushort tls[EPB * H];
    __shared__ __align__(16) ushort whi[H * 64];
    __shared__ __align__(16) ushort wlo[H * 64];

    const int tid = threadIdx.x, q = tid & 31, eo = tid >> 5;
    const int ebase = blockIdx.x * EPB;

    const int4* ghi = (const int4*)w2hiL;
    const int4* glo = (const int4*)w2loL;
    int4 rh0[2], rl0[2];
    rh0[0] = ghi[tid]; rh0[1] = ghi[tid + 512];
    rl0[0] = glo[tid]; rl0[1] = glo[tid + 512];

    const float* Wea = W1 + 256 * H;
    const float* wdv = W1 + 272 * H;
    float4 b1v = ld4(b1 + 4 * q);
    float4 wdq = ld4(wdv + 4 * q);

    int srcs[8], dsts8[8];
    float d2v[8];
#pragma unroll
    for (int i = 0; i < 8; ++i) {
        int j = ebase + eo * 8 + i;
        srcs[i] = src_s[j]; dsts8[i] = dst_s[j]; d2v[i] = d2_s[j];
    }
    float4 acc1[8];
#pragma unroll
    for (int i = 0; i < 8; ++i) {
        float4 a = f4add(ld4(Pd + (size_t)dsts8[i] * H + 4 * q),
                         ld4(Ps + (size_t)srcs[i] * H + 4 * q));
        a = f4add(a, b1v);
        fma4(a, d2v[i], wdq);
        acc1[i] = a;
    }
#pragma unroll
    for (int k4 = 0; k4 < 4; ++k4) {
        float4 w0 = ld4(Wea + (4 * k4 + 0) * H + 4 * q);
        float4 w1 = ld4(Wea + (4 * k4 + 1) * H + 4 * q);
        float4 w2 = ld4(Wea + (4 * k4 + 2) * H + 4 * q);
        float4 w3 = ld4(Wea + (4 * k4 + 3) * H + 4 * q);
#pragma unroll
        for (int i = 0; i < 8; ++i) {
            int j = ebase + eo * 8 + i;
            float4 av = ld4(ea_s + (size_t)j * DEA + 4 * k4);
            fma4(acc1[i], av.x, w0); fma4(acc1[i], av.y, w1);
            fma4(acc1[i], av.z, w2); fma4(acc1[i], av.w, w3);
        }
    }
#pragma unroll
    for (int i = 0; i < 8; ++i) {
        int el = eo * 8 + i;
        ushort4 tv;
        tv.x = f2bf(fmaxf(acc1[i].x, 0.f)); tv.y = f2bf(fmaxf(acc1[i].y, 0.f));
        tv.z = f2bf(fmaxf(acc1[i].z, 0.f)); tv.w = f2bf(fmaxf(acc1[i].w, 0.f));
        int tidx = el * H + ((4 * q) ^ ((el & 7) << 3));
        *reinterpret_cast<ushort4*>(&tls[tidx]) = tv;
    }

    ((int4*)whi)[tid] = rh0[0]; ((int4*)whi)[tid + 512] = rh0[1];
    ((int4*)wlo)[tid] = rl0[0]; ((int4*)wlo)[tid + 512] = rl0[1];
    int4 rh1[2], rl1[2];
    rh1[0] = ghi[1024 + tid]; rh1[1] = ghi[1024 + tid + 512];
    rl1[0] = glo[1024 + tid]; rl1[1] = glo[1024 + tid + 512];
    __syncthreads();

    const int lane = tid & 63, wvx = tid >> 6;
    const int col = lane & 15, g = lane >> 4;
    f32x4 acc[8];
#pragma unroll
    for (int nt = 0; nt < 8; ++nt) {
        float bb = b2[nt * 16 + col];
        acc[nt] = (f32x4){bb, bb, bb, bb};
    }
    const int arow = wvx * 16 + col;
    const int aswz = (arow & 7) << 3;

#define KSTEP(k0, kk0)                                                            \
    {                                                                             \
        short8 af = *(const short8*)&tls[arow * H + (((k0) + 8 * g) ^ aswz)];     \
        _Pragma("unroll")                                                         \
        for (int nt = 0; nt < 8; ++nt) {                                          \
            int brow = nt * 16 + col;                                             \
            int bidx = brow * 64 + (((kk0) + 8 * g) ^ ((brow & 7) << 3));         \
            short8 bh = *(const short8*)&whi[bidx];                               \
            short8 bl = *(const short8*)&wlo[bidx];                               \
            acc[nt] = __builtin_amdgcn_mfma_f32_16x16x32_bf16(af, bh, acc[nt], 0, 0, 0); \
            acc[nt] = __builtin_amdgcn_mfma_f32_16x16x32_bf16(af, bl, acc[nt], 0, 0, 0); \
        }                                                                         \
    }

    __builtin_amdgcn_s_setprio(1);
    KSTEP(0, 0)
    KSTEP(32, 32)
    __builtin_amdgcn_s_setprio(0);
    __syncthreads();
    ((int4*)whi)[tid] = rh1[0]; ((int4*)whi)[tid + 512] = rh1[1];
    ((int4*)wlo)[tid] = rl1[0]; ((int4*)wlo)[tid + 512] = rl1[1];
    __syncthreads();
    __builtin_amdgcn_s_setprio(1);
    KSTEP(64, 0)
    KSTEP(96, 32)
    __builtin_amdgcn_s_setprio(0);
#undef KSTEP

    const int growbase = ebase + wvx * 16 + g * 4;
    int dr[4];
#pragma unroll
    for (int r = 0; r < 4; ++r) dr[r] = dst_s[growbase + r];
    float vrun[8];
    int dcur = dr[0];
#pragma unroll
    for (int nt = 0; nt < 8; ++nt) vrun[nt] = fmaxf(acc[nt][0], 0.f);
#pragma unroll
    for (int r = 1; r < 4; ++r) {
        if (dr[r] != dcur) {
#pragma unroll
            for (int nt = 0; nt < 8; ++nt) {
                atomicAdd(&agg[(size_t)dcur * H + nt * 16 + col], vrun[nt]);
                vrun[nt] = fmaxf(acc[nt][r], 0.f);
            }
            dcur = dr[r];
        } else {
#pragma unroll
            for (int nt = 0; nt < 8; ++nt) vrun[nt] += fmaxf(acc[nt][r], 0.f);
        }
    }
#pragma unroll
    for (int nt = 0; nt < 8; ++nt)
        atomicAdd(&agg[(size_t)dcur * H + nt * 16 + col], vrun[nt]);
}

__global__ __launch_bounds__(256) void pool_kernel(const float* __restrict__ h,
    const int* __restrict__ batch, float* __restrict__ ssum,
    unsigned int* __restrict__ smaxk, float* __restrict__ cnt)
{
    const int tid = threadIdx.x, j = tid & 127, half = tid >> 7;
    const int nbase = blockIdx.x * 64;
    int cur = -1, rc = 0;
    float s = 0.f, mx = 0.f;
    for (int i = 0; i < 32; ++i) {
        int n = nbase + 2 * i + half;
        if (n >= NN) break;
        int g = batch[n];
        float v = h[(size_t)n * H + j];
        if (g != cur) {
            if (cur >= 0) {
                atomicAdd(&ssum[cur * H + j], s);
                atomicMax(&smaxk[cur * H + j], fkey(mx));
                if (j == 0) atomicAdd(&cnt[cur], (float)rc);
            }
            cur = g; s = v; mx = v; rc = 1;
        } else { s += v; mx = fmaxf(mx, v); rc++; }
    }
    if (cur >= 0) {
        atomicAdd(&ssum[cur * H + j], s);
        atomicMax(&smaxk[cur * H + j], fkey(mx));
        if (j == 0) atomicAdd(&cnt[cur], (float)rc);
    }
}

__global__ __launch_bounds__(128) void readout_kernel(const float* __restrict__ ssum,
    const unsigned int* __restrict__ smaxk, const float* __restrict__ cnt,
    const float* __restrict__ rW1, const float* __restrict__ rb1,
    const float* __restrict__ rW2, const float* __restrict__ rb2,
    const float* __restrict__ rW3, const float* __restrict__ rb3,
    float* __restrict__ out)
{
    __shared__ float p[384], h1[128], h2[64];
    const int g = blockIdx.x, j = threadIdx.x;
    float c = fmaxf(cnt[g], 1.0f);
    float sv = ssum[g * H + j];
    p[j] = sv / c;
    p[128 + j] = funkey(smaxk[g * H + j]);
    p[256 + j] = sv;
    __syncthreads();
    float a = rb1[j];
    for (int k = 0; k < 384; ++k) a = fmaf(p[k], rW1[k * H + j], a);
    h1[j] = fmaxf(a, 0.f);
    __syncthreads();
    if (j < 64) {
        float a2 = rb2[j];
        for (int k = 0; k < 128; ++k) a2 = fmaf(h1[k], rW2[k * 64 + j], a2);
        h2[j] = fmaxf(a2, 0.f);
    }
    __syncthreads();
    if (j < 64) {
        float t = h2[j] * rW3[j];
        for (int off = 32; off; off >>= 1) t += __shfl_down(t, off);
        if (j == 0) {
            float z = t + rb3[0];
            out[g] = z > 20.f ? z : log1pf(expf(z));
        }
    }
}

extern "C" void kernel_launch(void* const* d_in, const int* in_sizes, int n_in,
                              void* d_out, int out_size, void* d_ws, size_t ws_size,
                              hipStream_t stream)
{
    const float* x    = (const float*)d_in[0];
    const float* pos  = (const float*)d_in[1];
    const float* ea   = (const float*)d_in[2];
    const int*   ei   = (const int*)d_in[3];
    const int*   batch= (const int*)d_in[4];
    const float* encW = (const float*)d_in[5];
    const float* encb = (const float*)d_in[6];
    const float* eW1  = (const float*)d_in[7];
    const float* eb1  = (const float*)d_in[8];
    const float* eW2  = (const float*)d_in[9];
    const float* eb2  = (const float*)d_in[10];
    const float* nW1  = (const float*)d_in[11];
    const float* nb1  = (const float*)d_in[12];
    const float* nW2  = (const float*)d_in[13];
    const float* nb2  = (const float*)d_in[14];
    const float* rW1  = (const float*)d_in[15];
    const float* rb1  = (const float*)d_in[16];
    const float* rW2  = (const float*)d_in[17];
    const float* rb2  = (const float*)d_in[18];
    const float* rW3  = (const float*)d_in[19];
    const float* rb3  = (const float*)d_in[20];

    char* w = (char*)d_ws;
    size_t o = 0;
    auto alloc = [&](size_t bytes) -> char* {
        char* p = w + o; o += (bytes + 255) / 256 * 256; return p;
    };
    float* hA   = (float*)alloc((size_t)NN * H * 4);
    float* hB   = (float*)alloc((size_t)NN * H * 4);
    float* Pd   = (float*)alloc((size_t)NN * H * 4);
    float* Ps   = (float*)alloc((size_t)NN * H * 4);
    float* agg  = (float*)alloc((size_t)NN * H * 4);
    float* d2   = (float*)alloc((size_t)NE * 4);
    float* ssum = (float*)alloc((size_t)NG * H * 4);
    unsigned int* smaxk = (unsigned int*)alloc((size_t)NG * H * 4);
    float* cnt  = (float*)alloc((size_t)NG * 4);
    int*   deg    = (int*)alloc((size_t)NN * 4);
    int*   cursor = (int*)alloc((size_t)NN * 4);
    int*   src_s  = (int*)alloc((size_t)NE * 4);
    int*   dst_s  = (int*)alloc((size_t)NE * 4);
    float* ea_s   = (float*)alloc((size_t)NE * DEA * 4);
    float* d2_s   = (float*)alloc((size_t)NE * 4);
    ushort* w2hi  = (ushort*)alloc((size_t)NL * H * H * 2);
    ushort* w2lo  = (ushort*)alloc((size_t)NL * H * H * 2);
    ushort* nw1hi = (ushort*)alloc((size_t)NL * 256 * H * 2);
    ushort* nw1lo = (ushort*)alloc((size_t)NL * 256 * H * 2);
    ushort* nw2hi = (ushort*)alloc((size_t)NL * H * H * 2);
    ushort* nw2lo = (ushort*)alloc((size_t)NL * H * H * 2);
    ushort* w1dhi = (ushort*)alloc((size_t)NL * H * H * 2);
    ushort* w1dlo = (ushort*)alloc((size_t)NL * H * H * 2);
    ushort* w1shi = (ushort*)alloc((size_t)NL * H * H * 2);
    ushort* w1slo = (ushort*)alloc((size_t)NL * H * H * 2);
    (void)ws_size; (void)in_sizes; (void)n_in; (void)out_size;

    const int NB = (NN + 63) / 64;
    const int NBM = (NN + 127) / 128;
    const int EB = (NE + 255) / 256;

    hipMemsetAsync(deg, 0, (size_t)NN * 4, stream);
    dist2_kernel<<<EB, 256, 0, stream>>>(pos, ei, d2);
    hist_kernel<<<EB, 256, 0, stream>>>(ei, deg);
    scan_kernel<<<1, 256, 0, stream>>>(deg, cursor);
    scatter_kernel<<<EB, 256, 0, stream>>>(ei, ea, d2, cursor, src_s, dst_s, ea_s, d2_s);

    // weight prep: split-bf16, [n][k] panel-swizzled
    wprep_kernel<<<dim3(64, NL), 256, 0, stream>>>(eW2, w2hi, w2lo, H, H * H, H * H);
    wprep_kernel<<<dim3(128, NL), 256, 0, stream>>>(nW1, nw1hi, nw1lo, 256, 256 * H, 256 * H);
    wprep_kernel<<<dim3(64, NL), 256, 0, stream>>>(nW2, nw2hi, nw2lo, H, H * H, H * H);
    wprep_kernel<<<dim3(64, NL), 256, 0, stream>>>(eW1, w1dhi, w1dlo, H, 273 * H, H * H);
    wprep_kernel<<<dim3(64, NL), 256, 0, stream>>>(eW1 + 128 * H, w1shi, w1slo, H, 273 * H, H * H);

    encoder_kernel<<<NB, 256, 0, stream>>>(x, encW, encb, hA);

    float* hcur = hA;
    float* hnext = hB;
    for (int l = 0; l < NL; ++l) {
        hipMemsetAsync(agg, 0, (size_t)NN * H * 4, stream);
        const float* W1 = eW1 + (size_t)l * 273 * H;
        proj_mfma_kernel<<<NBM, 512, 0, stream>>>(hcur,
            w1dhi + (size_t)l * H * H, w1dlo + (size_t)l * H * H,
            w1shi + (size_t)l * H * H, w1slo + (size_t)l * H * H, Pd, Ps);
        edge_mfma_kernel<<<NE / EPB, 512, 0, stream>>>(Pd, Ps, ea_s, d2_s, src_s, dst_s,
            W1, eb1 + l * H, w2hi + (size_t)l * H * H, w2lo + (size_t)l * H * H,
            eb2 + l * H, agg);
        node_mfma_kernel<<<NBM, 512, 0, stream>>>(hcur, agg,
            nw1hi + (size_t)l * 256 * H, nw1lo + (size_t)l * 256 * H,
            nw2hi + (size_t)l * H * H, nw2lo + (size_t)l * H * H,
            nb1 + l * H, nb2 + l * H, hnext);
        float* tmp = hcur; hcur = hnext; hnext = tmp;
    }

    hipMemsetAsync(ssum, 0, (size_t)NG * H * 4, stream);
    hipMemsetAsync(smaxk, 0, (size_t)NG * H * 4, stream);
    hipMemsetAsync(cnt, 0, (size_t)NG * 4, stream);
    pool_kernel<<<NB, 256, 0, stream>>>(hcur, batch, ssum, smaxk, cnt);
    readout_kernel<<<NG, 128, 0, stream>>>(ssum, smaxk, cnt,
        rW1, rb1, rW2, rb2, rW3, rb3, (float*)d_out);
}